// Round 1
// baseline (195.854 us; speedup 1.0000x reference)
//
#include <hip/hip_runtime.h>
#include <hip/hip_bf16.h>

// GPT2 attention, B=2 S=2048 E=1024 H=16 hd=64.
// prep (cast X + transpose both weights); MFMA GEMM qkv (Q pre-scaled by 0.125
// in epilogue, LDS-transposed Vt); flash attention r11: swapped QK^T
// (mfma(K,Q)) -> P k-major in registers, in-register softmax, cvt_pk_bf16 +
// permlane32_swap/ds_swizzle lane exchange builds PV A-frags (no P LDS
// roundtrip), 128 q-rows/block = 2 strips/wave (2x K/V fragment reuse);
// 128x64-tile proj GEMM. 4 launches total.

typedef __attribute__((ext_vector_type(4))) float f32x4;
typedef __attribute__((ext_vector_type(8))) short short8;
typedef __attribute__((ext_vector_type(2))) unsigned int uint2v;

#define AS1 __attribute__((address_space(1)))
#define AS3 __attribute__((address_space(3)))

__device__ __forceinline__ void load_lds16(const void* g, void* l) {
    __builtin_amdgcn_global_load_lds((const AS1 void*)g, (AS3 void*)l, 16, 0, 0);
}

__device__ __forceinline__ unsigned short f2bf(float f) {       // RNE
    union { float f; unsigned int u; } v; v.f = f;
    unsigned int r = v.u + 0x7FFFu + ((v.u >> 16) & 1u);
    return (unsigned short)(r >> 16);
}

__device__ __forceinline__ int cvt_pk_bf16(float lo, float hi) {  // [bf16(lo) | bf16(hi)<<16]
    int r;
    asm("v_cvt_pk_bf16_f32 %0, %1, %2" : "=v"(r) : "v"(lo), "v"(hi));
    return r;
}

// ---------------------------------------------------------------- prep: cast + weight transposes
__device__ __forceinline__ void transpose_tile(
    const float* __restrict__ W, unsigned short* __restrict__ Wt,
    int K, int N, int bx, int by, int t) {
    __shared__ float tile[32][33];
    int k0 = by * 32, n0 = bx * 32;
    int r = t >> 3, c = (t & 7) * 4;
    float4 v = *(const float4*)&W[(size_t)(k0 + r) * N + n0 + c];
    tile[r][c] = v.x; tile[r][c + 1] = v.y; tile[r][c + 2] = v.z; tile[r][c + 3] = v.w;
    __syncthreads();
    int n = t >> 3; int kk = (t & 7) * 4;
    ushort4 o;
    o.x = f2bf(tile[kk + 0][n]);
    o.y = f2bf(tile[kk + 1][n]);
    o.z = f2bf(tile[kk + 2][n]);
    o.w = f2bf(tile[kk + 3][n]);
    *(ushort4*)&Wt[(size_t)(n0 + n) * K + k0 + kk] = o;
}

// grid 8192: [0,4096) cast X; [4096,7168) transpose W_attn; [7168,8192) transpose W_proj
__global__ __launch_bounds__(256) void prep(
    const float* __restrict__ hs, unsigned short* __restrict__ Xb,
    const float* __restrict__ W_attn, unsigned short* __restrict__ WaT,
    const float* __restrict__ W_proj, unsigned short* __restrict__ WpT) {
    int bid = blockIdx.x, t = threadIdx.x;
    if (bid < 4096) {
        int i = (bid * 256 + t) * 4;
        float4 v = *(const float4*)(hs + i);
        ushort4 o;
        o.x = f2bf(v.x); o.y = f2bf(v.y); o.z = f2bf(v.z); o.w = f2bf(v.w);
        *(ushort4*)(Xb + i) = o;
    } else if (bid < 7168) {
        int r = bid - 4096;                       // dims (96, 32)
        transpose_tile(W_attn, WaT, 1024, 3072, r % 96, r / 96, t);
    } else {
        int r = bid - 7168;                       // dims (32, 32)
        transpose_tile(W_proj, WpT, 1024, 1024, r % 32, r / 32, t);
    }
}

// ---------------------------------------------------------------- qkv GEMM (m97-style 128x128)
// C = Xb @ WaT^T + bias; qkv split -> qk[s][h*128+(q|k)] bf16 (Q cols scaled by
// 0.125 so attention needs no per-element scale); V -> Vt[b][h][d][s] via LDS
// transpose (coalesced 256B-row stores).
__global__ __launch_bounds__(256) void gemm_qkv(
    const unsigned short* __restrict__ A,
    const unsigned short* __restrict__ Bt,
    const float* __restrict__ bias,
    unsigned short* __restrict__ qk, unsigned short* __restrict__ Vt,
    int M, int N, int K) {
    __shared__ unsigned short Sh[8704];          // k-loop: As[4096]|Bs[4096]; epilogue: Tb[64][136]
    unsigned short* As = Sh;
    unsigned short* Bs = Sh + 4096;
    unsigned short* Tb = Sh;
    const int t = threadIdx.x, wave = t >> 6, lane = t & 63;
    const int l15 = lane & 15, quad = lane >> 4;
    const int m0 = blockIdx.y * 128, n0 = blockIdx.x * 128;
    const int srow = wave * 32 + (lane >> 2);
    const int sch = (lane & 3) * 8;
    const unsigned short* Ag = A + (size_t)(m0 + srow) * K + sch;
    const unsigned short* Bg = Bt + (size_t)(n0 + srow) * K + sch;
    unsigned short* AsW = &As[wave * 32 * 32];
    unsigned short* BsW = &Bs[wave * 32 * 32];
    const int wm = (wave >> 1) * 64, wn = (wave & 1) * 64;
    f32x4 acc[4][4] = {};
    for (int k0 = 0; k0 < K; k0 += 32) {
        load_lds16(Ag + k0, AsW);
        load_lds16(Ag + k0 + (size_t)16 * K, AsW + 16 * 32);
        load_lds16(Bg + k0, BsW);
        load_lds16(Bg + k0 + (size_t)16 * K, BsW + 16 * 32);
        __syncthreads();
        short8 af[4], bf[4];
#pragma unroll
        for (int i = 0; i < 4; ++i) {
            af[i] = *(const short8*)&As[(wm + i * 16 + l15) * 32 + quad * 8];
            bf[i] = *(const short8*)&Bs[(wn + i * 16 + l15) * 32 + quad * 8];
        }
#pragma unroll
        for (int mt = 0; mt < 4; ++mt)
#pragma unroll
            for (int nt = 0; nt < 4; ++nt)
                acc[mt][nt] = __builtin_amdgcn_mfma_f32_16x16x32_bf16(af[mt], bf[nt], acc[mt][nt], 0, 0, 0);
        __syncthreads();
    }
    // epilogue. V-cols of this block (if any) form one aligned 64-col half.
    const int rem = n0 % 192;                    // 0: no V; 128: half 0 is V; 64: half 1 is V
#pragma unroll
    for (int mt = 0; mt < 4; ++mt) {
        int mrow = m0 + wm + mt * 16 + quad * 4;
#pragma unroll
        for (int nt = 0; nt < 4; ++nt) {
            int col = n0 + wn + nt * 16 + l15;
            float bv = bias[col];
            int h = col / 192;
            int j = col - h * 192;
            if (j < 128) {       // Q or K -> qk buffer (both land at h*128 + j)
                float sc = (j < 64) ? 0.125f : 1.0f;   // fold 1/sqrt(hd) into Q
#pragma unroll
                for (int r = 0; r < 4; ++r)
                    qk[(size_t)(mrow + r) * 2048 + h * 128 + j] = f2bf((acc[mt][nt][r] + bv) * sc);
            } else {             // V -> LDS transpose buffer Tb[d][s_local]
                int d = j - 128;
                int s_local = wm + mt * 16 + quad * 4;
                ushort4 pk;
                pk.x = f2bf(acc[mt][nt][0] + bv);
                pk.y = f2bf(acc[mt][nt][1] + bv);
                pk.z = f2bf(acc[mt][nt][2] + bv);
                pk.w = f2bf(acc[mt][nt][3] + bv);
                *(ushort4*)&Tb[d * 136 + s_local] = pk;
            }
        }
    }
    if (rem != 0) {              // block-uniform: barrier legal
        __syncthreads();
        int vhalf = (rem == 64) ? 1 : 0;
        int h = (n0 + vhalf * 64) / 192;
        int b = m0 >> 11;
        unsigned short* vbase = Vt + ((size_t)(b * 16 + h) * 64) * 2048 + (m0 & 2047);
        int drow = t >> 4, ch = (t & 15) * 8;    // 16 rows/pass x 16 chunks of 16B
#pragma unroll
        for (int rr = 0; rr < 4; ++rr) {
            int d = rr * 16 + drow;
            *(uint4*)(vbase + (size_t)d * 2048 + ch) = *(const uint4*)&Tb[d * 136 + ch];
        }
    }
}

// ---------------------------------------------------------------- proj GEMM, 128x64 tile
__global__ __launch_bounds__(256) void gemm_proj(
    const unsigned short* __restrict__ A,
    const unsigned short* __restrict__ Bt,
    const float* __restrict__ bias,
    float* __restrict__ C, int M, int N, int K) {
    __shared__ unsigned short As[128 * 32];
    __shared__ unsigned short Bs[64 * 32];
    const int t = threadIdx.x, wave = t >> 6, lane = t & 63;
    const int l15 = lane & 15, quad = lane >> 4;
    const int m0 = blockIdx.y * 128, n0 = blockIdx.x * 64;
    const int srowA = wave * 32 + (lane >> 2);
    const int sch = (lane & 3) * 8;
    const unsigned short* Ag = A + (size_t)(m0 + srowA) * K + sch;
    const unsigned short* Bg = Bt + (size_t)(n0 + wave * 16 + (lane >> 2)) * K + sch;
    unsigned short* AsW = &As[wave * 32 * 32];
    unsigned short* BsW = &Bs[wave * 16 * 32];
    const int wm = (wave >> 1) * 64, wn = (wave & 1) * 32;
    f32x4 acc[4][2] = {};
    for (int k0 = 0; k0 < K; k0 += 32) {
        load_lds16(Ag + k0, AsW);
        load_lds16(Ag + k0 + (size_t)16 * K, AsW + 16 * 32);
        load_lds16(Bg + k0, BsW);
        __syncthreads();
        short8 af[4], bf[2];
#pragma unroll
        for (int i = 0; i < 4; ++i)
            af[i] = *(const short8*)&As[(wm + i * 16 + l15) * 32 + quad * 8];
#pragma unroll
        for (int i = 0; i < 2; ++i)
            bf[i] = *(const short8*)&Bs[(wn + i * 16 + l15) * 32 + quad * 8];
#pragma unroll
        for (int mt = 0; mt < 4; ++mt)
#pragma unroll
            for (int nt = 0; nt < 2; ++nt)
                acc[mt][nt] = __builtin_amdgcn_mfma_f32_16x16x32_bf16(af[mt], bf[nt], acc[mt][nt], 0, 0, 0);
        __syncthreads();
    }
#pragma unroll
    for (int mt = 0; mt < 4; ++mt) {
        int mrow = m0 + wm + mt * 16 + quad * 4;
#pragma unroll
        for (int nt = 0; nt < 2; ++nt) {
            int col = n0 + wn + nt * 16 + l15;
            float bv = bias[col];
#pragma unroll
            for (int r = 0; r < 4; ++r)
                C[(size_t)(mrow + r) * N + col] = acc[mt][nt][r] + bv;
        }
    }
}

// ---------------------------------------------------------------- flash attention r11
// Swapped QK^T: s[nt] = mfma(K,Q) -> lane (quad,l15) reg r holds
// P[k = 16*nt + 4*quad + r][q = l15].  cvt_pk packs k-pairs (r even/odd) into
// dwords; permlane32_swap + ds_swizzle(xor16) + cndmask redistributes so each
// lane holds the PV A-frag P[q=l15][k = 32*km + 8*quad + 0..7].
__device__ __forceinline__ void build_af(const int (&pk)[4][2], int qpar, short8 (&af)[2]) {
#pragma unroll
    for (int km = 0; km < 2; ++km) {
        uint2v r0 = __builtin_amdgcn_permlane32_swap(
            (unsigned)pk[2 * km][0], (unsigned)pk[2 * km + 1][0], false, false);
        uint2v r1 = __builtin_amdgcn_permlane32_swap(
            (unsigned)pk[2 * km][1], (unsigned)pk[2 * km + 1][1], false, false);
        int Ap0 = (int)r0[0], Bp0 = (int)r0[1];
        int Ap1 = (int)r1[0], Bp1 = (int)r1[1];
        int z0 = qpar ? Ap0 : Bp0;               // source-side pick for the xor16 hop
        int z1 = qpar ? Ap1 : Bp1;
        int w0 = __builtin_amdgcn_ds_swizzle(z0, 0x401F);   // xor lane^16
        int w1 = __builtin_amdgcn_ds_swizzle(z1, 0x401F);
        int f0 = qpar ? w0 : Ap0, f1 = qpar ? w1 : Ap1;
        int g0 = qpar ? Bp0 : w0, g1 = qpar ? Bp1 : w1;
        int4 v = {f0, f1, g0, g1};
        af[km] = __builtin_bit_cast(short8, v);
    }
}

// One block per (b, h, 128-row q-tile). 2 strips of 16 q-rows per wave -> each
// K/V LDS fragment feeds 2 MFMAs. Register double-buffered K/V staging.
// Block pairing: bids i and i+256 have qt summing to 15 (balanced per CU).
__global__ __launch_bounds__(256) void attn2(
    const unsigned short* __restrict__ qk,   // [B*S][2048], head h: [h*128+q | +64 k]
    const unsigned short* __restrict__ Vt,   // [B*H][64][2048]
    unsigned short* __restrict__ out) {      // [B*S][1024]
    const int S = 2048;
    __shared__ unsigned short Ks[64][72];
    __shared__ unsigned short Vts[64][72];
    const int t = threadIdx.x, wave = t >> 6, lane = t & 63;
    const int l15 = lane & 15, quad = lane >> 4, qpar = quad & 1;
    const int bid = blockIdx.x;
    const int qt = (bid < 256) ? (15 - (bid >> 5)) : ((bid - 256) >> 5);
    const int bh = bid & 31;
    const int b = bh >> 4, h = bh & 15;
    const unsigned short* qkb = qk + (size_t)b * S * 2048 + h * 128;
    const unsigned short* vtb = Vt + (size_t)bh * 64 * 2048;

    const int q0 = qt * 128 + wave * 32;         // wave's first q row (2 strips of 16)
    short8 qf[2][2];                             // [strip][km]
#pragma unroll
    for (int sp = 0; sp < 2; ++sp) {
        int qr = q0 + sp * 16 + l15;
#pragma unroll
        for (int km = 0; km < 2; ++km)
            qf[sp][km] = *(const short8*)(qkb + (size_t)qr * 2048 + km * 32 + quad * 8);
    }
    f32x4 o0[4] = {}, o1[4] = {};
    float lr0 = 0.f, lr1 = 0.f;

    const int srow8 = t >> 3, chunk8 = (t & 7) * 8;
    const int vd = t >> 2, vch = (t & 3) * 8;
    const int KT = qt * 2 + 2;

    uint4 kreg0 = *(const uint4*)(qkb + (size_t)srow8 * 2048 + 64 + chunk8);
    uint4 kreg1 = *(const uint4*)(qkb + (size_t)(32 + srow8) * 2048 + 64 + chunk8);
    uint4 vreg0 = *(const uint4*)(vtb + (size_t)vd * 2048 + vch);
    uint4 vreg1 = *(const uint4*)(vtb + (size_t)vd * 2048 + vch + 32);

    const int qg0 = q0 + l15, qg1 = q0 + 16 + l15;
    const int q1max = q0 + 31;

    for (int kt = 0; kt < KT; ++kt) {
        __syncthreads();
        *(uint4*)&Ks[srow8][chunk8] = kreg0;
        *(uint4*)&Ks[32 + srow8][chunk8] = kreg1;
        *(uint4*)&Vts[vd][vch] = vreg0;
        *(uint4*)&Vts[vd][vch + 32] = vreg1;
        __syncthreads();
        if (kt + 1 < KT) {
            int kn = (kt + 1) * 64;
            kreg0 = *(const uint4*)(qkb + (size_t)(kn + srow8) * 2048 + 64 + chunk8);
            kreg1 = *(const uint4*)(qkb + (size_t)(kn + 32 + srow8) * 2048 + 64 + chunk8);
            vreg0 = *(const uint4*)(vtb + (size_t)vd * 2048 + kn + vch);
            vreg1 = *(const uint4*)(vtb + (size_t)vd * 2048 + kn + vch + 32);
        }
        const int kb = kt * 64;
        if (kb > q1max) continue;   // fully masked for this wave; barriers already done

        // ---- QK^T (swapped): each kf fragment feeds both strips
        f32x4 s0[4] = {}, s1[4] = {};
        __builtin_amdgcn_s_setprio(1);
#pragma unroll
        for (int km = 0; km < 2; ++km)
#pragma unroll
            for (int nt = 0; nt < 4; ++nt) {
                short8 kf = *(const short8*)&Ks[nt * 16 + l15][km * 32 + quad * 8];
                s0[nt] = __builtin_amdgcn_mfma_f32_16x16x32_bf16(kf, qf[0][km], s0[nt], 0, 0, 0);
                s1[nt] = __builtin_amdgcn_mfma_f32_16x16x32_bf16(kf, qf[1][km], s1[nt], 0, 0, 0);
            }
        __builtin_amdgcn_s_setprio(0);

        // ---- causal mask (diag region only); Q pre-scaled so s is final logit
        const int ka = kb + quad * 4;
        if (kb + 63 > q0) {
#pragma unroll
            for (int nt = 0; nt < 4; ++nt)
#pragma unroll
                for (int r = 0; r < 4; ++r) {
                    if (ka + nt * 16 + r > qg0) s0[nt][r] = -1e30f;
                    if (ka + nt * 16 + r > qg1) s1[nt][r] = -1e30f;
                }
        }

        // ---- softmax (no-max) + pack to bf16 pairs, fully in registers
        int pk0[4][2], pk1[4][2];
        float a0 = 0.f, a1 = 0.f;
#pragma unroll
        for (int nt = 0; nt < 4; ++nt) {
            float pa[4], pb[4];
#pragma unroll
            for (int r = 0; r < 4; ++r) {
                pa[r] = __expf(s0[nt][r]);
                pb[r] = __expf(s1[nt][r]);
                a0 += pa[r]; a1 += pb[r];
            }
            pk0[nt][0] = cvt_pk_bf16(pa[0], pa[1]);
            pk0[nt][1] = cvt_pk_bf16(pa[2], pa[3]);
            pk1[nt][0] = cvt_pk_bf16(pb[0], pb[1]);
            pk1[nt][1] = cvt_pk_bf16(pb[2], pb[3]);
        }
        lr0 += a0; lr1 += a1;

        // ---- lane exchange: PV A-frags in registers
        short8 af0[2], af1[2];
        build_af(pk0, qpar, af0);
        build_af(pk1, qpar, af1);

        // ---- PV: each vf fragment feeds both strips
        __builtin_amdgcn_s_setprio(1);
#pragma unroll
        for (int km = 0; km < 2; ++km)
#pragma unroll
            for (int nt = 0; nt < 4; ++nt) {
                short8 vf = *(const short8*)&Vts[nt * 16 + l15][km * 32 + quad * 8];
                o0[nt] = __builtin_amdgcn_mfma_f32_16x16x32_bf16(af0[km], vf, o0[nt], 0, 0, 0);
                o1[nt] = __builtin_amdgcn_mfma_f32_16x16x32_bf16(af1[km], vf, o1[nt], 0, 0, 0);
            }
        __builtin_amdgcn_s_setprio(0);
    }

    // ---- epilogue: cross-quad row-sum reduce (once), normalize, store
    float t0 = lr0 + __shfl_xor(lr0, 16);
    t0 += __shfl_xor(t0, 32);
    float t1 = lr1 + __shfl_xor(lr1, 16);
    t1 += __shfl_xor(t1, 32);
    unsigned short* ob = out + (size_t)b * S * 1024 + h * 64;
#pragma unroll
    for (int r = 0; r < 4; ++r) {
        float i0 = 1.0f / __shfl(t0, quad * 4 + r);   // sum for q_local = quad*4+r lives at lane l15==q_local
        float i1 = 1.0f / __shfl(t1, quad * 4 + r);
        size_t r0 = (size_t)(q0 + quad * 4 + r) * 1024;
        size_t r1 = (size_t)(q0 + 16 + quad * 4 + r) * 1024;
#pragma unroll
        for (int nt = 0; nt < 4; ++nt) {
            ob[r0 + nt * 16 + l15] = f2bf(o0[nt][r] * i0);
            ob[r1 + nt * 16 + l15] = f2bf(o1[nt][r] * i1);
        }
    }
}

// ----------------------------------------------------------------
extern "C" void kernel_launch(void* const* d_in, const int* in_sizes, int n_in,
                              void* d_out, int out_size, void* d_ws, size_t ws_size,
                              hipStream_t stream) {
    const float* hs     = (const float*)d_in[0];
    const float* W_attn = (const float*)d_in[1];
    const float* b_attn = (const float*)d_in[2];
    const float* W_proj = (const float*)d_in[3];
    const float* b_proj = (const float*)d_in[4];
    float* out = (float*)d_out;

    const int B = 2, S = 2048, E = 1024;
    const int M = B * S;        // 4096
    const int N3 = 3 * E;       // 3072

    unsigned short* Xb  = (unsigned short*)d_ws;          // M*E
    unsigned short* WaT = Xb + (size_t)M * E;             // N3*E
    unsigned short* WpT = WaT + (size_t)N3 * E;           // E*E
    unsigned short* qkb = WpT + (size_t)E * E;            // M*2048
    unsigned short* Vt  = qkb + (size_t)M * 2048;         // M*E
    unsigned short* ao  = Vt + (size_t)M * E;             // M*E

    prep<<<dim3(8192), 256, 0, stream>>>(hs, Xb, W_attn, WaT, W_proj, WpT);

    gemm_qkv<<<dim3(N3 / 128, M / 128), 256, 0, stream>>>(Xb, WaT, b_attn, qkb, Vt, M, N3, E);

    attn2<<<dim3(512), 256, 0, stream>>>(qkb, Vt, ao);

    gemm_proj<<<dim3(E / 64, M / 128), 256, 0, stream>>>(ao, WpT, b_proj, out, M, E, E);
}

// Round 2
// 184.039 us; speedup vs baseline: 1.0642x; 1.0642x over previous
//
#include <hip/hip_runtime.h>
#include <hip/hip_bf16.h>

// GPT2 attention, B=2 S=2048 E=1024 H=16 hd=64.
// prep (cast X + transpose both weights); MFMA GEMM qkv (Q pre-scaled by 0.125
// in epilogue, LDS-transposed Vt); flash attention r12: swapped QK^T
// (mfma(K,Q)) -> P k-major in registers, in-register softmax, cvt_pk_bf16 +
// permlane32_swap/ds_swizzle lane exchange builds PV A-frags; 8 waves x 16
// q-rows = 128 rows/block; double-buffered K/V LDS with ONE barrier per
// k-step; register-prefetched staging. 128x64-tile proj GEMM. 4 launches.

typedef __attribute__((ext_vector_type(4))) float f32x4;
typedef __attribute__((ext_vector_type(8))) short short8;
typedef __attribute__((ext_vector_type(2))) unsigned int uint2v;

#define AS1 __attribute__((address_space(1)))
#define AS3 __attribute__((address_space(3)))

__device__ __forceinline__ void load_lds16(const void* g, void* l) {
    __builtin_amdgcn_global_load_lds((const AS1 void*)g, (AS3 void*)l, 16, 0, 0);
}

__device__ __forceinline__ unsigned short f2bf(float f) {       // RNE
    union { float f; unsigned int u; } v; v.f = f;
    unsigned int r = v.u + 0x7FFFu + ((v.u >> 16) & 1u);
    return (unsigned short)(r >> 16);
}

__device__ __forceinline__ int cvt_pk_bf16(float lo, float hi) {  // [bf16(lo) | bf16(hi)<<16]
    int r;
    asm("v_cvt_pk_bf16_f32 %0, %1, %2" : "=v"(r) : "v"(lo), "v"(hi));
    return r;
}

// ---------------------------------------------------------------- prep: cast + weight transposes
__device__ __forceinline__ void transpose_tile(
    const float* __restrict__ W, unsigned short* __restrict__ Wt,
    int K, int N, int bx, int by, int t) {
    __shared__ float tile[32][33];
    int k0 = by * 32, n0 = bx * 32;
    int r = t >> 3, c = (t & 7) * 4;
    float4 v = *(const float4*)&W[(size_t)(k0 + r) * N + n0 + c];
    tile[r][c] = v.x; tile[r][c + 1] = v.y; tile[r][c + 2] = v.z; tile[r][c + 3] = v.w;
    __syncthreads();
    int n = t >> 3; int kk = (t & 7) * 4;
    ushort4 o;
    o.x = f2bf(tile[kk + 0][n]);
    o.y = f2bf(tile[kk + 1][n]);
    o.z = f2bf(tile[kk + 2][n]);
    o.w = f2bf(tile[kk + 3][n]);
    *(ushort4*)&Wt[(size_t)(n0 + n) * K + k0 + kk] = o;
}

// grid 8192: [0,4096) cast X; [4096,7168) transpose W_attn; [7168,8192) transpose W_proj
__global__ __launch_bounds__(256) void prep(
    const float* __restrict__ hs, unsigned short* __restrict__ Xb,
    const float* __restrict__ W_attn, unsigned short* __restrict__ WaT,
    const float* __restrict__ W_proj, unsigned short* __restrict__ WpT) {
    int bid = blockIdx.x, t = threadIdx.x;
    if (bid < 4096) {
        int i = (bid * 256 + t) * 4;
        float4 v = *(const float4*)(hs + i);
        ushort4 o;
        o.x = f2bf(v.x); o.y = f2bf(v.y); o.z = f2bf(v.z); o.w = f2bf(v.w);
        *(ushort4*)(Xb + i) = o;
    } else if (bid < 7168) {
        int r = bid - 4096;                       // dims (96, 32)
        transpose_tile(W_attn, WaT, 1024, 3072, r % 96, r / 96, t);
    } else {
        int r = bid - 7168;                       // dims (32, 32)
        transpose_tile(W_proj, WpT, 1024, 1024, r % 32, r / 32, t);
    }
}

// ---------------------------------------------------------------- qkv GEMM (m97-style 128x128)
// C = Xb @ WaT^T + bias; qkv split -> qk[s][h*128+(q|k)] bf16 (Q cols scaled by
// 0.125 so attention needs no per-element scale); V -> Vt[b][h][d][s] via LDS
// transpose (coalesced 256B-row stores).
__global__ __launch_bounds__(256) void gemm_qkv(
    const unsigned short* __restrict__ A,
    const unsigned short* __restrict__ Bt,
    const float* __restrict__ bias,
    unsigned short* __restrict__ qk, unsigned short* __restrict__ Vt,
    int M, int N, int K) {
    __shared__ unsigned short Sh[8704];          // k-loop: As[4096]|Bs[4096]; epilogue: Tb[64][136]
    unsigned short* As = Sh;
    unsigned short* Bs = Sh + 4096;
    unsigned short* Tb = Sh;
    const int t = threadIdx.x, wave = t >> 6, lane = t & 63;
    const int l15 = lane & 15, quad = lane >> 4;
    const int m0 = blockIdx.y * 128, n0 = blockIdx.x * 128;
    const int srow = wave * 32 + (lane >> 2);
    const int sch = (lane & 3) * 8;
    const unsigned short* Ag = A + (size_t)(m0 + srow) * K + sch;
    const unsigned short* Bg = Bt + (size_t)(n0 + srow) * K + sch;
    unsigned short* AsW = &As[wave * 32 * 32];
    unsigned short* BsW = &Bs[wave * 32 * 32];
    const int wm = (wave >> 1) * 64, wn = (wave & 1) * 64;
    f32x4 acc[4][4] = {};
    for (int k0 = 0; k0 < K; k0 += 32) {
        load_lds16(Ag + k0, AsW);
        load_lds16(Ag + k0 + (size_t)16 * K, AsW + 16 * 32);
        load_lds16(Bg + k0, BsW);
        load_lds16(Bg + k0 + (size_t)16 * K, BsW + 16 * 32);
        __syncthreads();
        short8 af[4], bf[4];
#pragma unroll
        for (int i = 0; i < 4; ++i) {
            af[i] = *(const short8*)&As[(wm + i * 16 + l15) * 32 + quad * 8];
            bf[i] = *(const short8*)&Bs[(wn + i * 16 + l15) * 32 + quad * 8];
        }
#pragma unroll
        for (int mt = 0; mt < 4; ++mt)
#pragma unroll
            for (int nt = 0; nt < 4; ++nt)
                acc[mt][nt] = __builtin_amdgcn_mfma_f32_16x16x32_bf16(af[mt], bf[nt], acc[mt][nt], 0, 0, 0);
        __syncthreads();
    }
    // epilogue. V-cols of this block (if any) form one aligned 64-col half.
    const int rem = n0 % 192;                    // 0: no V; 128: half 0 is V; 64: half 1 is V
#pragma unroll
    for (int mt = 0; mt < 4; ++mt) {
        int mrow = m0 + wm + mt * 16 + quad * 4;
#pragma unroll
        for (int nt = 0; nt < 4; ++nt) {
            int col = n0 + wn + nt * 16 + l15;
            float bv = bias[col];
            int h = col / 192;
            int j = col - h * 192;
            if (j < 128) {       // Q or K -> qk buffer (both land at h*128 + j)
                float sc = (j < 64) ? 0.125f : 1.0f;   // fold 1/sqrt(hd) into Q
#pragma unroll
                for (int r = 0; r < 4; ++r)
                    qk[(size_t)(mrow + r) * 2048 + h * 128 + j] = f2bf((acc[mt][nt][r] + bv) * sc);
            } else {             // V -> LDS transpose buffer Tb[d][s_local]
                int d = j - 128;
                int s_local = wm + mt * 16 + quad * 4;
                ushort4 pk;
                pk.x = f2bf(acc[mt][nt][0] + bv);
                pk.y = f2bf(acc[mt][nt][1] + bv);
                pk.z = f2bf(acc[mt][nt][2] + bv);
                pk.w = f2bf(acc[mt][nt][3] + bv);
                *(ushort4*)&Tb[d * 136 + s_local] = pk;
            }
        }
    }
    if (rem != 0) {              // block-uniform: barrier legal
        __syncthreads();
        int vhalf = (rem == 64) ? 1 : 0;
        int h = (n0 + vhalf * 64) / 192;
        int b = m0 >> 11;
        unsigned short* vbase = Vt + ((size_t)(b * 16 + h) * 64) * 2048 + (m0 & 2047);
        int drow = t >> 4, ch = (t & 15) * 8;    // 16 rows/pass x 16 chunks of 16B
#pragma unroll
        for (int rr = 0; rr < 4; ++rr) {
            int d = rr * 16 + drow;
            *(uint4*)(vbase + (size_t)d * 2048 + ch) = *(const uint4*)&Tb[d * 136 + ch];
        }
    }
}

// ---------------------------------------------------------------- proj GEMM, 128x64 tile
__global__ __launch_bounds__(256) void gemm_proj(
    const unsigned short* __restrict__ A,
    const unsigned short* __restrict__ Bt,
    const float* __restrict__ bias,
    float* __restrict__ C, int M, int N, int K) {
    __shared__ unsigned short As[128 * 32];
    __shared__ unsigned short Bs[64 * 32];
    const int t = threadIdx.x, wave = t >> 6, lane = t & 63;
    const int l15 = lane & 15, quad = lane >> 4;
    const int m0 = blockIdx.y * 128, n0 = blockIdx.x * 64;
    const int srowA = wave * 32 + (lane >> 2);
    const int sch = (lane & 3) * 8;
    const unsigned short* Ag = A + (size_t)(m0 + srowA) * K + sch;
    const unsigned short* Bg = Bt + (size_t)(n0 + wave * 16 + (lane >> 2)) * K + sch;
    unsigned short* AsW = &As[wave * 32 * 32];
    unsigned short* BsW = &Bs[wave * 16 * 32];
    const int wm = (wave >> 1) * 64, wn = (wave & 1) * 32;
    f32x4 acc[4][2] = {};
    for (int k0 = 0; k0 < K; k0 += 32) {
        load_lds16(Ag + k0, AsW);
        load_lds16(Ag + k0 + (size_t)16 * K, AsW + 16 * 32);
        load_lds16(Bg + k0, BsW);
        __syncthreads();
        short8 af[4], bf[2];
#pragma unroll
        for (int i = 0; i < 4; ++i)
            af[i] = *(const short8*)&As[(wm + i * 16 + l15) * 32 + quad * 8];
#pragma unroll
        for (int i = 0; i < 2; ++i)
            bf[i] = *(const short8*)&Bs[(wn + i * 16 + l15) * 32 + quad * 8];
#pragma unroll
        for (int mt = 0; mt < 4; ++mt)
#pragma unroll
            for (int nt = 0; nt < 2; ++nt)
                acc[mt][nt] = __builtin_amdgcn_mfma_f32_16x16x32_bf16(af[mt], bf[nt], acc[mt][nt], 0, 0, 0);
        __syncthreads();
    }
#pragma unroll
    for (int mt = 0; mt < 4; ++mt) {
        int mrow = m0 + wm + mt * 16 + quad * 4;
#pragma unroll
        for (int nt = 0; nt < 2; ++nt) {
            int col = n0 + wn + nt * 16 + l15;
            float bv = bias[col];
#pragma unroll
            for (int r = 0; r < 4; ++r)
                C[(size_t)(mrow + r) * N + col] = acc[mt][nt][r] + bv;
        }
    }
}

// ---------------------------------------------------------------- flash attention r12
// Swapped QK^T: s[nt] = mfma(K,Q) -> lane (quad,l15) reg r holds
// P[k = 16*nt + 4*quad + r][q = l15].  cvt_pk packs k-pairs (r even/odd) into
// dwords; permlane32_swap + ds_swizzle(xor16) + cndmask redistributes so each
// lane holds the PV A-frag P[q=l15][k = 32*km + 8*quad + 0..7].
__device__ __forceinline__ void build_af(const int (&pk)[4][2], int qpar, short8 (&af)[2]) {
#pragma unroll
    for (int km = 0; km < 2; ++km) {
        uint2v r0 = __builtin_amdgcn_permlane32_swap(
            (unsigned)pk[2 * km][0], (unsigned)pk[2 * km + 1][0], false, false);
        uint2v r1 = __builtin_amdgcn_permlane32_swap(
            (unsigned)pk[2 * km][1], (unsigned)pk[2 * km + 1][1], false, false);
        int Ap0 = (int)r0[0], Bp0 = (int)r0[1];
        int Ap1 = (int)r1[0], Bp1 = (int)r1[1];
        int z0 = qpar ? Ap0 : Bp0;               // source-side pick for the xor16 hop
        int z1 = qpar ? Ap1 : Bp1;
        int w0 = __builtin_amdgcn_ds_swizzle(z0, 0x401F);   // xor lane^16
        int w1 = __builtin_amdgcn_ds_swizzle(z1, 0x401F);
        int f0 = qpar ? w0 : Ap0, f1 = qpar ? w1 : Ap1;
        int g0 = qpar ? Bp0 : w0, g1 = qpar ? Bp1 : w1;
        int4 v = {f0, f1, g0, g1};
        af[km] = __builtin_bit_cast(short8, v);
    }
}

// One block per (b, h, 128-row q-tile); 8 waves x 16 q-rows. Double-buffered
// K/V LDS: one barrier per k-step; next tile prefetched into VGPRs during
// compute. Block pairing: bids i and i+256 have qt summing to 15.
__global__ __launch_bounds__(512, 4) void attn3(
    const unsigned short* __restrict__ qk,   // [B*S][2048], head h: [h*128+q | +64 k]
    const unsigned short* __restrict__ Vt,   // [B*H][64][2048]
    unsigned short* __restrict__ out) {      // [B*S][1024]
    const int S = 2048;
    __shared__ unsigned short Ks[2][64][72];
    __shared__ unsigned short Vts[2][64][72];
    const int t = threadIdx.x, wave = t >> 6, lane = t & 63;
    const int l15 = lane & 15, quad = lane >> 4, qpar = quad & 1;
    const int bid = blockIdx.x;
    const int qt = (bid < 256) ? (15 - (bid >> 5)) : ((bid - 256) >> 5);
    const int bh = bid & 31;
    const int b = bh >> 4, h = bh & 15;
    const unsigned short* qkb = qk + (size_t)b * S * 2048 + h * 128;
    const unsigned short* vtb = Vt + (size_t)bh * 64 * 2048;

    const int q0 = qt * 128 + wave * 16;         // wave's 16 q-rows
    short8 qf[2];
#pragma unroll
    for (int km = 0; km < 2; ++km)
        qf[km] = *(const short8*)(qkb + (size_t)(q0 + l15) * 2048 + km * 32 + quad * 8);
    f32x4 o[4] = {};
    float lrun = 0.f;

    // staging: 512 threads x 16B = 8KB = one 64x64 bf16 tile per buffer
    const int srow8 = t >> 3, chunk8 = (t & 7) * 8;
    const int KT = qt * 2 + 2;

    uint4 kreg = *(const uint4*)(qkb + (size_t)srow8 * 2048 + 64 + chunk8);
    uint4 vreg = *(const uint4*)(vtb + (size_t)srow8 * 2048 + chunk8);

    const int qg = q0 + l15;
    const int qmax = q0 + 15;

    for (int kt = 0; kt < KT; ++kt) {
        const int cur = kt & 1;
        *(uint4*)&Ks[cur][srow8][chunk8] = kreg;
        *(uint4*)&Vts[cur][srow8][chunk8] = vreg;
        __syncthreads();
        if (kt + 1 < KT) {
            int kn = (kt + 1) * 64;
            kreg = *(const uint4*)(qkb + (size_t)(kn + srow8) * 2048 + 64 + chunk8);
            vreg = *(const uint4*)(vtb + (size_t)srow8 * 2048 + kn + chunk8);
        }
        const int kb = kt * 64;
        if (kb > qmax) continue;   // fully masked for this wave

        // ---- QK^T (swapped)
        f32x4 s[4] = {};
        __builtin_amdgcn_s_setprio(1);
#pragma unroll
        for (int km = 0; km < 2; ++km)
#pragma unroll
            for (int nt = 0; nt < 4; ++nt) {
                short8 kf = *(const short8*)&Ks[cur][nt * 16 + l15][km * 32 + quad * 8];
                s[nt] = __builtin_amdgcn_mfma_f32_16x16x32_bf16(kf, qf[km], s[nt], 0, 0, 0);
            }
        __builtin_amdgcn_s_setprio(0);

        // ---- causal mask (diag tile only); Q pre-scaled so s is final logit
        if (kb + 63 > q0) {
            const int ka = kb + quad * 4;
#pragma unroll
            for (int nt = 0; nt < 4; ++nt)
#pragma unroll
                for (int r = 0; r < 4; ++r)
                    if (ka + nt * 16 + r > qg) s[nt][r] = -1e30f;
        }

        // ---- softmax (no-max) + pack to bf16 pairs, fully in registers
        int pk[4][2];
        float a0 = 0.f;
#pragma unroll
        for (int nt = 0; nt < 4; ++nt) {
            float pa[4];
#pragma unroll
            for (int r = 0; r < 4; ++r) {
                pa[r] = __expf(s[nt][r]);
                a0 += pa[r];
            }
            pk[nt][0] = cvt_pk_bf16(pa[0], pa[1]);
            pk[nt][1] = cvt_pk_bf16(pa[2], pa[3]);
        }
        lrun += a0;

        // ---- lane exchange: PV A-frags in registers
        short8 af[2];
        build_af(pk, qpar, af);

        // ---- PV
        __builtin_amdgcn_s_setprio(1);
#pragma unroll
        for (int km = 0; km < 2; ++km)
#pragma unroll
            for (int nt = 0; nt < 4; ++nt) {
                short8 vf = *(const short8*)&Vts[cur][nt * 16 + l15][km * 32 + quad * 8];
                o[nt] = __builtin_amdgcn_mfma_f32_16x16x32_bf16(af[km], vf, o[nt], 0, 0, 0);
            }
        __builtin_amdgcn_s_setprio(0);
    }

    // ---- epilogue: cross-quad row-sum reduce, normalize, store
    float t0 = lrun + __shfl_xor(lrun, 16);
    t0 += __shfl_xor(t0, 32);
    unsigned short* ob = out + (size_t)b * S * 1024 + h * 64;
#pragma unroll
    for (int r = 0; r < 4; ++r) {
        float i0 = 1.0f / __shfl(t0, quad * 4 + r);   // sum for q_local lives at lane l15==q_local
        size_t r0 = (size_t)(q0 + quad * 4 + r) * 1024;
#pragma unroll
        for (int nt = 0; nt < 4; ++nt)
            ob[r0 + nt * 16 + l15] = f2bf(o[nt][r] * i0);
    }
}

// ----------------------------------------------------------------
extern "C" void kernel_launch(void* const* d_in, const int* in_sizes, int n_in,
                              void* d_out, int out_size, void* d_ws, size_t ws_size,
                              hipStream_t stream) {
    const float* hs     = (const float*)d_in[0];
    const float* W_attn = (const float*)d_in[1];
    const float* b_attn = (const float*)d_in[2];
    const float* W_proj = (const float*)d_in[3];
    const float* b_proj = (const float*)d_in[4];
    float* out = (float*)d_out;

    const int B = 2, S = 2048, E = 1024;
    const int M = B * S;        // 4096
    const int N3 = 3 * E;       // 3072

    unsigned short* Xb  = (unsigned short*)d_ws;          // M*E
    unsigned short* WaT = Xb + (size_t)M * E;             // N3*E
    unsigned short* WpT = WaT + (size_t)N3 * E;           // E*E
    unsigned short* qkb = WpT + (size_t)E * E;            // M*2048
    unsigned short* Vt  = qkb + (size_t)M * 2048;         // M*E
    unsigned short* ao  = Vt + (size_t)M * E;             // M*E

    prep<<<dim3(8192), 256, 0, stream>>>(hs, Xb, W_attn, WaT, W_proj, WpT);

    gemm_qkv<<<dim3(N3 / 128, M / 128), 256, 0, stream>>>(Xb, WaT, b_attn, qkb, Vt, M, N3, E);

    attn3<<<dim3(512), 512, 0, stream>>>(qkb, Vt, ao);

    gemm_proj<<<dim3(E / 64, M / 128), 256, 0, stream>>>(ao, WpT, b_proj, out, M, E, E);
}

// Round 3
// 176.136 us; speedup vs baseline: 1.1119x; 1.0449x over previous
//
#include <hip/hip_runtime.h>
#include <hip/hip_bf16.h>

// GPT2 attention, B=2 S=2048 E=1024 H=16 hd=64.
// prep (cast X + transpose both weights); MFMA GEMM qkv r13: 128x128 tile,
// DOUBLE-BUFFERED global_load_lds staging with one barrier per k-step
// (prefetch k+1 while computing k); Q pre-scaled by 0.125 in epilogue,
// LDS-transposed Vt. flash attention r12 (swapped QK^T, in-register softmax,
// permlane/ds_swizzle PV frags, 8 waves, dbuf LDS, 1 barrier/step).
// proj GEMM gets the same dbuf 1-barrier treatment. 4 launches.

typedef __attribute__((ext_vector_type(4))) float f32x4;
typedef __attribute__((ext_vector_type(8))) short short8;
typedef __attribute__((ext_vector_type(2))) unsigned int uint2v;

#define AS1 __attribute__((address_space(1)))
#define AS3 __attribute__((address_space(3)))

__device__ __forceinline__ void load_lds16(const void* g, void* l) {
    __builtin_amdgcn_global_load_lds((const AS1 void*)g, (AS3 void*)l, 16, 0, 0);
}

__device__ __forceinline__ unsigned short f2bf(float f) {       // RNE
    union { float f; unsigned int u; } v; v.f = f;
    unsigned int r = v.u + 0x7FFFu + ((v.u >> 16) & 1u);
    return (unsigned short)(r >> 16);
}

__device__ __forceinline__ int cvt_pk_bf16(float lo, float hi) {  // [bf16(lo) | bf16(hi)<<16]
    int r;
    asm("v_cvt_pk_bf16_f32 %0, %1, %2" : "=v"(r) : "v"(lo), "v"(hi));
    return r;
}

// ---------------------------------------------------------------- prep: cast + weight transposes
__device__ __forceinline__ void transpose_tile(
    const float* __restrict__ W, unsigned short* __restrict__ Wt,
    int K, int N, int bx, int by, int t) {
    __shared__ float tile[32][33];
    int k0 = by * 32, n0 = bx * 32;
    int r = t >> 3, c = (t & 7) * 4;
    float4 v = *(const float4*)&W[(size_t)(k0 + r) * N + n0 + c];
    tile[r][c] = v.x; tile[r][c + 1] = v.y; tile[r][c + 2] = v.z; tile[r][c + 3] = v.w;
    __syncthreads();
    int n = t >> 3; int kk = (t & 7) * 4;
    ushort4 o;
    o.x = f2bf(tile[kk + 0][n]);
    o.y = f2bf(tile[kk + 1][n]);
    o.z = f2bf(tile[kk + 2][n]);
    o.w = f2bf(tile[kk + 3][n]);
    *(ushort4*)&Wt[(size_t)(n0 + n) * K + k0 + kk] = o;
}

// grid 8192: [0,4096) cast X; [4096,7168) transpose W_attn; [7168,8192) transpose W_proj
__global__ __launch_bounds__(256) void prep(
    const float* __restrict__ hs, unsigned short* __restrict__ Xb,
    const float* __restrict__ W_attn, unsigned short* __restrict__ WaT,
    const float* __restrict__ W_proj, unsigned short* __restrict__ WpT) {
    int bid = blockIdx.x, t = threadIdx.x;
    if (bid < 4096) {
        int i = (bid * 256 + t) * 4;
        float4 v = *(const float4*)(hs + i);
        ushort4 o;
        o.x = f2bf(v.x); o.y = f2bf(v.y); o.z = f2bf(v.z); o.w = f2bf(v.w);
        *(ushort4*)(Xb + i) = o;
    } else if (bid < 7168) {
        int r = bid - 4096;                       // dims (96, 32)
        transpose_tile(W_attn, WaT, 1024, 3072, r % 96, r / 96, t);
    } else {
        int r = bid - 7168;                       // dims (32, 32)
        transpose_tile(W_proj, WpT, 1024, 1024, r % 32, r / 32, t);
    }
}

// ---------------------------------------------------------------- qkv GEMM r13 (128x128, dbuf)
// C = Xb @ WaT^T + bias; qkv split -> qk[s][h*128+(q|k)] bf16 (Q cols scaled by
// 0.125); V -> Vt[b][h][d][s] via LDS transpose. Double-buffered staging:
// one barrier per k-step, loads for k+1 issued right after the barrier so the
// forced vmcnt(0) drain at the NEXT barrier is cheap.
__global__ __launch_bounds__(256) void gemm_qkv(
    const unsigned short* __restrict__ A,
    const unsigned short* __restrict__ Bt,
    const float* __restrict__ bias,
    unsigned short* __restrict__ qk, unsigned short* __restrict__ Vt,
    int M, int N, int K) {
    __shared__ unsigned short Sh[2][8192];       // [buf][As 4096 | Bs 4096]; Tb[64][136] overlays
    unsigned short* Tb = &Sh[0][0];
    const int t = threadIdx.x, wave = t >> 6, lane = t & 63;
    const int l15 = lane & 15, quad = lane >> 4;
    const int m0 = blockIdx.y * 128, n0 = blockIdx.x * 128;
    const int srow = wave * 32 + (lane >> 2);
    const int sch = (lane & 3) * 8;
    const unsigned short* Ag = A + (size_t)(m0 + srow) * K + sch;
    const unsigned short* Bg = Bt + (size_t)(n0 + srow) * K + sch;
    const int wOff = wave * 1024;                // per-wave 32x32 stage region
    const int wm = (wave >> 1) * 64, wn = (wave & 1) * 64;
    f32x4 acc[4][4] = {};
    const int NSTEP = K / 32;                    // 32
    // prologue: stage k=0 into buf 0
    load_lds16(Ag, &Sh[0][wOff]);
    load_lds16(Ag + (size_t)16 * K, &Sh[0][wOff + 512]);
    load_lds16(Bg, &Sh[0][4096 + wOff]);
    load_lds16(Bg + (size_t)16 * K, &Sh[0][4096 + wOff + 512]);
    for (int kt = 0; kt < NSTEP; ++kt) {
        const int cur = kt & 1;
        const unsigned short* As = &Sh[cur][0];
        const unsigned short* Bs = &Sh[cur][4096];
        __syncthreads();                         // buf[cur] ready; buf[cur^1] reads done
        if (kt + 1 < NSTEP) {
            const int k1 = (kt + 1) * 32;
            unsigned short* An = &Sh[cur ^ 1][0];
            unsigned short* Bn = &Sh[cur ^ 1][4096];
            load_lds16(Ag + k1, An + wOff);
            load_lds16(Ag + k1 + (size_t)16 * K, An + wOff + 512);
            load_lds16(Bg + k1, Bn + wOff);
            load_lds16(Bg + k1 + (size_t)16 * K, Bn + wOff + 512);
        }
        short8 af[4], bf[4];
#pragma unroll
        for (int i = 0; i < 4; ++i) {
            af[i] = *(const short8*)&As[(wm + i * 16 + l15) * 32 + quad * 8];
            bf[i] = *(const short8*)&Bs[(wn + i * 16 + l15) * 32 + quad * 8];
        }
        __builtin_amdgcn_s_setprio(1);
#pragma unroll
        for (int mt = 0; mt < 4; ++mt)
#pragma unroll
            for (int nt = 0; nt < 4; ++nt)
                acc[mt][nt] = __builtin_amdgcn_mfma_f32_16x16x32_bf16(af[mt], bf[nt], acc[mt][nt], 0, 0, 0);
        __builtin_amdgcn_s_setprio(0);
    }
    __syncthreads();                             // all k-loop LDS reads done before Tb overlay
    // epilogue. V-cols of this block (if any) form one aligned 64-col half.
    const int rem = n0 % 192;                    // 0: no V; 128: half 0 is V; 64: half 1 is V
#pragma unroll
    for (int mt = 0; mt < 4; ++mt) {
        int mrow = m0 + wm + mt * 16 + quad * 4;
#pragma unroll
        for (int nt = 0; nt < 4; ++nt) {
            int col = n0 + wn + nt * 16 + l15;
            float bv = bias[col];
            int h = col / 192;
            int j = col - h * 192;
            if (j < 128) {       // Q or K -> qk buffer (both land at h*128 + j)
                float sc = (j < 64) ? 0.125f : 1.0f;   // fold 1/sqrt(hd) into Q
#pragma unroll
                for (int r = 0; r < 4; ++r)
                    qk[(size_t)(mrow + r) * 2048 + h * 128 + j] = f2bf((acc[mt][nt][r] + bv) * sc);
            } else {             // V -> LDS transpose buffer Tb[d][s_local]
                int d = j - 128;
                int s_local = wm + mt * 16 + quad * 4;
                ushort4 pk;
                pk.x = f2bf(acc[mt][nt][0] + bv);
                pk.y = f2bf(acc[mt][nt][1] + bv);
                pk.z = f2bf(acc[mt][nt][2] + bv);
                pk.w = f2bf(acc[mt][nt][3] + bv);
                *(ushort4*)&Tb[d * 136 + s_local] = pk;
            }
        }
    }
    if (rem != 0) {              // block-uniform: barrier legal
        __syncthreads();
        int vhalf = (rem == 64) ? 1 : 0;
        int h = (n0 + vhalf * 64) / 192;
        int b = m0 >> 11;
        unsigned short* vbase = Vt + ((size_t)(b * 16 + h) * 64) * 2048 + (m0 & 2047);
        int drow = t >> 4, ch = (t & 15) * 8;    // 16 rows/pass x 16 chunks of 16B
#pragma unroll
        for (int rr = 0; rr < 4; ++rr) {
            int d = rr * 16 + drow;
            *(uint4*)(vbase + (size_t)d * 2048 + ch) = *(const uint4*)&Tb[d * 136 + ch];
        }
    }
}

// ---------------------------------------------------------------- proj GEMM r13, 128x64 tile, dbuf
__global__ __launch_bounds__(256) void gemm_proj(
    const unsigned short* __restrict__ A,
    const unsigned short* __restrict__ Bt,
    const float* __restrict__ bias,
    float* __restrict__ C, int M, int N, int K) {
    __shared__ unsigned short Sh[2][6144];       // [buf][As 4096 | Bs 2048]
    const int t = threadIdx.x, wave = t >> 6, lane = t & 63;
    const int l15 = lane & 15, quad = lane >> 4;
    const int m0 = blockIdx.y * 128, n0 = blockIdx.x * 64;
    const int srowA = wave * 32 + (lane >> 2);
    const int sch = (lane & 3) * 8;
    const unsigned short* Ag = A + (size_t)(m0 + srowA) * K + sch;
    const unsigned short* Bg = Bt + (size_t)(n0 + wave * 16 + (lane >> 2)) * K + sch;
    const int aOff = wave * 1024, bOff = wave * 512;
    const int wm = (wave >> 1) * 64, wn = (wave & 1) * 32;
    f32x4 acc[4][2] = {};
    const int NSTEP = K / 32;
    load_lds16(Ag, &Sh[0][aOff]);
    load_lds16(Ag + (size_t)16 * K, &Sh[0][aOff + 512]);
    load_lds16(Bg, &Sh[0][4096 + bOff]);
    for (int kt = 0; kt < NSTEP; ++kt) {
        const int cur = kt & 1;
        const unsigned short* As = &Sh[cur][0];
        const unsigned short* Bs = &Sh[cur][4096];
        __syncthreads();
        if (kt + 1 < NSTEP) {
            const int k1 = (kt + 1) * 32;
            load_lds16(Ag + k1, &Sh[cur ^ 1][aOff]);
            load_lds16(Ag + k1 + (size_t)16 * K, &Sh[cur ^ 1][aOff + 512]);
            load_lds16(Bg + k1, &Sh[cur ^ 1][4096 + bOff]);
        }
        short8 af[4], bf[2];
#pragma unroll
        for (int i = 0; i < 4; ++i)
            af[i] = *(const short8*)&As[(wm + i * 16 + l15) * 32 + quad * 8];
#pragma unroll
        for (int i = 0; i < 2; ++i)
            bf[i] = *(const short8*)&Bs[(wn + i * 16 + l15) * 32 + quad * 8];
        __builtin_amdgcn_s_setprio(1);
#pragma unroll
        for (int mt = 0; mt < 4; ++mt)
#pragma unroll
            for (int nt = 0; nt < 2; ++nt)
                acc[mt][nt] = __builtin_amdgcn_mfma_f32_16x16x32_bf16(af[mt], bf[nt], acc[mt][nt], 0, 0, 0);
        __builtin_amdgcn_s_setprio(0);
    }
#pragma unroll
    for (int mt = 0; mt < 4; ++mt) {
        int mrow = m0 + wm + mt * 16 + quad * 4;
#pragma unroll
        for (int nt = 0; nt < 2; ++nt) {
            int col = n0 + wn + nt * 16 + l15;
            float bv = bias[col];
#pragma unroll
            for (int r = 0; r < 4; ++r)
                C[(size_t)(mrow + r) * N + col] = acc[mt][nt][r] + bv;
        }
    }
}

// ---------------------------------------------------------------- flash attention r12
// Swapped QK^T: s[nt] = mfma(K,Q) -> lane (quad,l15) reg r holds
// P[k = 16*nt + 4*quad + r][q = l15].  cvt_pk packs k-pairs (r even/odd) into
// dwords; permlane32_swap + ds_swizzle(xor16) + cndmask redistributes so each
// lane holds the PV A-frag P[q=l15][k = 32*km + 8*quad + 0..7].
__device__ __forceinline__ void build_af(const int (&pk)[4][2], int qpar, short8 (&af)[2]) {
#pragma unroll
    for (int km = 0; km < 2; ++km) {
        uint2v r0 = __builtin_amdgcn_permlane32_swap(
            (unsigned)pk[2 * km][0], (unsigned)pk[2 * km + 1][0], false, false);
        uint2v r1 = __builtin_amdgcn_permlane32_swap(
            (unsigned)pk[2 * km][1], (unsigned)pk[2 * km + 1][1], false, false);
        int Ap0 = (int)r0[0], Bp0 = (int)r0[1];
        int Ap1 = (int)r1[0], Bp1 = (int)r1[1];
        int z0 = qpar ? Ap0 : Bp0;               // source-side pick for the xor16 hop
        int z1 = qpar ? Ap1 : Bp1;
        int w0 = __builtin_amdgcn_ds_swizzle(z0, 0x401F);   // xor lane^16
        int w1 = __builtin_amdgcn_ds_swizzle(z1, 0x401F);
        int f0 = qpar ? w0 : Ap0, f1 = qpar ? w1 : Ap1;
        int g0 = qpar ? Bp0 : w0, g1 = qpar ? Bp1 : w1;
        int4 v = {f0, f1, g0, g1};
        af[km] = __builtin_bit_cast(short8, v);
    }
}

// One block per (b, h, 128-row q-tile); 8 waves x 16 q-rows. Double-buffered
// K/V LDS: one barrier per k-step; next tile prefetched into VGPRs during
// compute. Block pairing: bids i and i+256 have qt summing to 15.
__global__ __launch_bounds__(512, 4) void attn3(
    const unsigned short* __restrict__ qk,   // [B*S][2048], head h: [h*128+q | +64 k]
    const unsigned short* __restrict__ Vt,   // [B*H][64][2048]
    unsigned short* __restrict__ out) {      // [B*S][1024]
    const int S = 2048;
    __shared__ unsigned short Ks[2][64][72];
    __shared__ unsigned short Vts[2][64][72];
    const int t = threadIdx.x, wave = t >> 6, lane = t & 63;
    const int l15 = lane & 15, quad = lane >> 4, qpar = quad & 1;
    const int bid = blockIdx.x;
    const int qt = (bid < 256) ? (15 - (bid >> 5)) : ((bid - 256) >> 5);
    const int bh = bid & 31;
    const int b = bh >> 4, h = bh & 15;
    const unsigned short* qkb = qk + (size_t)b * S * 2048 + h * 128;
    const unsigned short* vtb = Vt + (size_t)bh * 64 * 2048;

    const int q0 = qt * 128 + wave * 16;         // wave's 16 q-rows
    short8 qf[2];
#pragma unroll
    for (int km = 0; km < 2; ++km)
        qf[km] = *(const short8*)(qkb + (size_t)(q0 + l15) * 2048 + km * 32 + quad * 8);
    f32x4 o[4] = {};
    float lrun = 0.f;

    // staging: 512 threads x 16B = 8KB = one 64x64 bf16 tile per buffer
    const int srow8 = t >> 3, chunk8 = (t & 7) * 8;
    const int KT = qt * 2 + 2;

    uint4 kreg = *(const uint4*)(qkb + (size_t)srow8 * 2048 + 64 + chunk8);
    uint4 vreg = *(const uint4*)(vtb + (size_t)srow8 * 2048 + chunk8);

    const int qg = q0 + l15;
    const int qmax = q0 + 15;

    for (int kt = 0; kt < KT; ++kt) {
        const int cur = kt & 1;
        *(uint4*)&Ks[cur][srow8][chunk8] = kreg;
        *(uint4*)&Vts[cur][srow8][chunk8] = vreg;
        __syncthreads();
        if (kt + 1 < KT) {
            int kn = (kt + 1) * 64;
            kreg = *(const uint4*)(qkb + (size_t)(kn + srow8) * 2048 + 64 + chunk8);
            vreg = *(const uint4*)(vtb + (size_t)srow8 * 2048 + kn + chunk8);
        }
        const int kb = kt * 64;
        if (kb > qmax) continue;   // fully masked for this wave

        // ---- QK^T (swapped)
        f32x4 s[4] = {};
        __builtin_amdgcn_s_setprio(1);
#pragma unroll
        for (int km = 0; km < 2; ++km)
#pragma unroll
            for (int nt = 0; nt < 4; ++nt) {
                short8 kf = *(const short8*)&Ks[cur][nt * 16 + l15][km * 32 + quad * 8];
                s[nt] = __builtin_amdgcn_mfma_f32_16x16x32_bf16(kf, qf[km], s[nt], 0, 0, 0);
            }
        __builtin_amdgcn_s_setprio(0);

        // ---- causal mask (diag tile only); Q pre-scaled so s is final logit
        if (kb + 63 > q0) {
            const int ka = kb + quad * 4;
#pragma unroll
            for (int nt = 0; nt < 4; ++nt)
#pragma unroll
                for (int r = 0; r < 4; ++r)
                    if (ka + nt * 16 + r > qg) s[nt][r] = -1e30f;
        }

        // ---- softmax (no-max) + pack to bf16 pairs, fully in registers
        int pk[4][2];
        float a0 = 0.f;
#pragma unroll
        for (int nt = 0; nt < 4; ++nt) {
            float pa[4];
#pragma unroll
            for (int r = 0; r < 4; ++r) {
                pa[r] = __expf(s[nt][r]);
                a0 += pa[r];
            }
            pk[nt][0] = cvt_pk_bf16(pa[0], pa[1]);
            pk[nt][1] = cvt_pk_bf16(pa[2], pa[3]);
        }
        lrun += a0;

        // ---- lane exchange: PV A-frags in registers
        short8 af[2];
        build_af(pk, qpar, af);

        // ---- PV
        __builtin_amdgcn_s_setprio(1);
#pragma unroll
        for (int km = 0; km < 2; ++km)
#pragma unroll
            for (int nt = 0; nt < 4; ++nt) {
                short8 vf = *(const short8*)&Vts[cur][nt * 16 + l15][km * 32 + quad * 8];
                o[nt] = __builtin_amdgcn_mfma_f32_16x16x32_bf16(af[km], vf, o[nt], 0, 0, 0);
            }
        __builtin_amdgcn_s_setprio(0);
    }

    // ---- epilogue: cross-quad row-sum reduce, normalize, store
    float t0 = lrun + __shfl_xor(lrun, 16);
    t0 += __shfl_xor(t0, 32);
    unsigned short* ob = out + (size_t)b * S * 1024 + h * 64;
#pragma unroll
    for (int r = 0; r < 4; ++r) {
        float i0 = 1.0f / __shfl(t0, quad * 4 + r);   // sum for q_local lives at lane l15==q_local
        size_t r0 = (size_t)(q0 + quad * 4 + r) * 1024;
#pragma unroll
        for (int nt = 0; nt < 4; ++nt)
            ob[r0 + nt * 16 + l15] = f2bf(o[nt][r] * i0);
    }
}

// ----------------------------------------------------------------
extern "C" void kernel_launch(void* const* d_in, const int* in_sizes, int n_in,
                              void* d_out, int out_size, void* d_ws, size_t ws_size,
                              hipStream_t stream) {
    const float* hs     = (const float*)d_in[0];
    const float* W_attn = (const float*)d_in[1];
    const float* b_attn = (const float*)d_in[2];
    const float* W_proj = (const float*)d_in[3];
    const float* b_proj = (const float*)d_in[4];
    float* out = (float*)d_out;

    const int B = 2, S = 2048, E = 1024;
    const int M = B * S;        // 4096
    const int N3 = 3 * E;       // 3072

    unsigned short* Xb  = (unsigned short*)d_ws;          // M*E
    unsigned short* WaT = Xb + (size_t)M * E;             // N3*E
    unsigned short* WpT = WaT + (size_t)N3 * E;           // E*E
    unsigned short* qkb = WpT + (size_t)E * E;            // M*2048
    unsigned short* Vt  = qkb + (size_t)M * 2048;         // M*E
    unsigned short* ao  = Vt + (size_t)M * E;             // M*E

    prep<<<dim3(8192), 256, 0, stream>>>(hs, Xb, W_attn, WaT, W_proj, WpT);

    gemm_qkv<<<dim3(N3 / 128, M / 128), 256, 0, stream>>>(Xb, WaT, b_attn, qkb, Vt, M, N3, E);

    attn3<<<dim3(512), 512, 0, stream>>>(qkb, Vt, ao);

    gemm_proj<<<dim3(E / 64, M / 128), 256, 0, stream>>>(ao, WpT, b_proj, out, M, E, E);
}

// Round 4
// 175.142 us; speedup vs baseline: 1.1183x; 1.0057x over previous
//
#include <hip/hip_runtime.h>
#include <hip/hip_bf16.h>

// GPT2 attention, B=2 S=2048 E=1024 H=16 hd=64.
// prep (cast X + transpose both weights); MFMA GEMM qkv r13 (128x128, dbuf
// global_load_lds, 1 barrier/k-step, Q pre-scaled 0.125, LDS-transposed Vt);
// flash attention r14: 32x32x16 MFMA core, 4 waves x 32 q-rows = 128/block,
// swapped QK^T -> P k-major in regs, lane-local row-sum, 2-permlane frag
// build (no cndmask), XOR-swizzled stride-128B K/V LDS, dbuf 1 barrier/step;
// proj GEMM r13 (dbuf). 4 launches.

typedef __attribute__((ext_vector_type(4))) float f32x4;
typedef __attribute__((ext_vector_type(16))) float f32x16;
typedef __attribute__((ext_vector_type(8))) short short8;
typedef __attribute__((ext_vector_type(2))) unsigned int uint2v;

#define AS1 __attribute__((address_space(1)))
#define AS3 __attribute__((address_space(3)))

__device__ __forceinline__ void load_lds16(const void* g, void* l) {
    __builtin_amdgcn_global_load_lds((const AS1 void*)g, (AS3 void*)l, 16, 0, 0);
}

__device__ __forceinline__ unsigned short f2bf(float f) {       // RNE
    union { float f; unsigned int u; } v; v.f = f;
    unsigned int r = v.u + 0x7FFFu + ((v.u >> 16) & 1u);
    return (unsigned short)(r >> 16);
}

__device__ __forceinline__ int cvt_pk_bf16(float lo, float hi) {  // [bf16(lo) | bf16(hi)<<16]
    int r;
    asm("v_cvt_pk_bf16_f32 %0, %1, %2" : "=v"(r) : "v"(lo), "v"(hi));
    return r;
}

// ---------------------------------------------------------------- prep: cast + weight transposes
__device__ __forceinline__ void transpose_tile(
    const float* __restrict__ W, unsigned short* __restrict__ Wt,
    int K, int N, int bx, int by, int t) {
    __shared__ float tile[32][33];
    int k0 = by * 32, n0 = bx * 32;
    int r = t >> 3, c = (t & 7) * 4;
    float4 v = *(const float4*)&W[(size_t)(k0 + r) * N + n0 + c];
    tile[r][c] = v.x; tile[r][c + 1] = v.y; tile[r][c + 2] = v.z; tile[r][c + 3] = v.w;
    __syncthreads();
    int n = t >> 3; int kk = (t & 7) * 4;
    ushort4 o;
    o.x = f2bf(tile[kk + 0][n]);
    o.y = f2bf(tile[kk + 1][n]);
    o.z = f2bf(tile[kk + 2][n]);
    o.w = f2bf(tile[kk + 3][n]);
    *(ushort4*)&Wt[(size_t)(n0 + n) * K + k0 + kk] = o;
}

// grid 8192: [0,4096) cast X; [4096,7168) transpose W_attn; [7168,8192) transpose W_proj
__global__ __launch_bounds__(256) void prep(
    const float* __restrict__ hs, unsigned short* __restrict__ Xb,
    const float* __restrict__ W_attn, unsigned short* __restrict__ WaT,
    const float* __restrict__ W_proj, unsigned short* __restrict__ WpT) {
    int bid = blockIdx.x, t = threadIdx.x;
    if (bid < 4096) {
        int i = (bid * 256 + t) * 4;
        float4 v = *(const float4*)(hs + i);
        ushort4 o;
        o.x = f2bf(v.x); o.y = f2bf(v.y); o.z = f2bf(v.z); o.w = f2bf(v.w);
        *(ushort4*)(Xb + i) = o;
    } else if (bid < 7168) {
        int r = bid - 4096;                       // dims (96, 32)
        transpose_tile(W_attn, WaT, 1024, 3072, r % 96, r / 96, t);
    } else {
        int r = bid - 7168;                       // dims (32, 32)
        transpose_tile(W_proj, WpT, 1024, 1024, r % 32, r / 32, t);
    }
}

// ---------------------------------------------------------------- qkv GEMM r13 (128x128, dbuf)
__global__ __launch_bounds__(256) void gemm_qkv(
    const unsigned short* __restrict__ A,
    const unsigned short* __restrict__ Bt,
    const float* __restrict__ bias,
    unsigned short* __restrict__ qk, unsigned short* __restrict__ Vt,
    int M, int N, int K) {
    __shared__ unsigned short Sh[2][8192];       // [buf][As 4096 | Bs 4096]; Tb[64][136] overlays
    unsigned short* Tb = &Sh[0][0];
    const int t = threadIdx.x, wave = t >> 6, lane = t & 63;
    const int l15 = lane & 15, quad = lane >> 4;
    const int m0 = blockIdx.y * 128, n0 = blockIdx.x * 128;
    const int srow = wave * 32 + (lane >> 2);
    const int sch = (lane & 3) * 8;
    const unsigned short* Ag = A + (size_t)(m0 + srow) * K + sch;
    const unsigned short* Bg = Bt + (size_t)(n0 + srow) * K + sch;
    const int wOff = wave * 1024;                // per-wave 32x32 stage region
    const int wm = (wave >> 1) * 64, wn = (wave & 1) * 64;
    f32x4 acc[4][4] = {};
    const int NSTEP = K / 32;                    // 32
    load_lds16(Ag, &Sh[0][wOff]);
    load_lds16(Ag + (size_t)16 * K, &Sh[0][wOff + 512]);
    load_lds16(Bg, &Sh[0][4096 + wOff]);
    load_lds16(Bg + (size_t)16 * K, &Sh[0][4096 + wOff + 512]);
    for (int kt = 0; kt < NSTEP; ++kt) {
        const int cur = kt & 1;
        const unsigned short* As = &Sh[cur][0];
        const unsigned short* Bs = &Sh[cur][4096];
        __syncthreads();                         // buf[cur] ready; buf[cur^1] reads done
        if (kt + 1 < NSTEP) {
            const int k1 = (kt + 1) * 32;
            unsigned short* An = &Sh[cur ^ 1][0];
            unsigned short* Bn = &Sh[cur ^ 1][4096];
            load_lds16(Ag + k1, An + wOff);
            load_lds16(Ag + k1 + (size_t)16 * K, An + wOff + 512);
            load_lds16(Bg + k1, Bn + wOff);
            load_lds16(Bg + k1 + (size_t)16 * K, Bn + wOff + 512);
        }
        short8 af[4], bf[4];
#pragma unroll
        for (int i = 0; i < 4; ++i) {
            af[i] = *(const short8*)&As[(wm + i * 16 + l15) * 32 + quad * 8];
            bf[i] = *(const short8*)&Bs[(wn + i * 16 + l15) * 32 + quad * 8];
        }
        __builtin_amdgcn_s_setprio(1);
#pragma unroll
        for (int mt = 0; mt < 4; ++mt)
#pragma unroll
            for (int nt = 0; nt < 4; ++nt)
                acc[mt][nt] = __builtin_amdgcn_mfma_f32_16x16x32_bf16(af[mt], bf[nt], acc[mt][nt], 0, 0, 0);
        __builtin_amdgcn_s_setprio(0);
    }
    __syncthreads();                             // all k-loop LDS reads done before Tb overlay
    const int rem = n0 % 192;                    // 0: no V; 128: half 0 is V; 64: half 1 is V
#pragma unroll
    for (int mt = 0; mt < 4; ++mt) {
        int mrow = m0 + wm + mt * 16 + quad * 4;
#pragma unroll
        for (int nt = 0; nt < 4; ++nt) {
            int col = n0 + wn + nt * 16 + l15;
            float bv = bias[col];
            int h = col / 192;
            int j = col - h * 192;
            if (j < 128) {       // Q or K -> qk buffer (both land at h*128 + j)
                float sc = (j < 64) ? 0.125f : 1.0f;   // fold 1/sqrt(hd) into Q
#pragma unroll
                for (int r = 0; r < 4; ++r)
                    qk[(size_t)(mrow + r) * 2048 + h * 128 + j] = f2bf((acc[mt][nt][r] + bv) * sc);
            } else {             // V -> LDS transpose buffer Tb[d][s_local]
                int d = j - 128;
                int s_local = wm + mt * 16 + quad * 4;
                ushort4 pk;
                pk.x = f2bf(acc[mt][nt][0] + bv);
                pk.y = f2bf(acc[mt][nt][1] + bv);
                pk.z = f2bf(acc[mt][nt][2] + bv);
                pk.w = f2bf(acc[mt][nt][3] + bv);
                *(ushort4*)&Tb[d * 136 + s_local] = pk;
            }
        }
    }
    if (rem != 0) {              // block-uniform: barrier legal
        __syncthreads();
        int vhalf = (rem == 64) ? 1 : 0;
        int h = (n0 + vhalf * 64) / 192;
        int b = m0 >> 11;
        unsigned short* vbase = Vt + ((size_t)(b * 16 + h) * 64) * 2048 + (m0 & 2047);
        int drow = t >> 4, ch = (t & 15) * 8;    // 16 rows/pass x 16 chunks of 16B
#pragma unroll
        for (int rr = 0; rr < 4; ++rr) {
            int d = rr * 16 + drow;
            *(uint4*)(vbase + (size_t)d * 2048 + ch) = *(const uint4*)&Tb[d * 136 + ch];
        }
    }
}

// ---------------------------------------------------------------- proj GEMM r13, 128x64 tile, dbuf
__global__ __launch_bounds__(256) void gemm_proj(
    const unsigned short* __restrict__ A,
    const unsigned short* __restrict__ Bt,
    const float* __restrict__ bias,
    float* __restrict__ C, int M, int N, int K) {
    __shared__ unsigned short Sh[2][6144];       // [buf][As 4096 | Bs 2048]
    const int t = threadIdx.x, wave = t >> 6, lane = t & 63;
    const int l15 = lane & 15, quad = lane >> 4;
    const int m0 = blockIdx.y * 128, n0 = blockIdx.x * 64;
    const int srowA = wave * 32 + (lane >> 2);
    const int sch = (lane & 3) * 8;
    const unsigned short* Ag = A + (size_t)(m0 + srowA) * K + sch;
    const unsigned short* Bg = Bt + (size_t)(n0 + wave * 16 + (lane >> 2)) * K + sch;
    const int aOff = wave * 1024, bOff = wave * 512;
    const int wm = (wave >> 1) * 64, wn = (wave & 1) * 32;
    f32x4 acc[4][2] = {};
    const int NSTEP = K / 32;
    load_lds16(Ag, &Sh[0][aOff]);
    load_lds16(Ag + (size_t)16 * K, &Sh[0][aOff + 512]);
    load_lds16(Bg, &Sh[0][4096 + bOff]);
    for (int kt = 0; kt < NSTEP; ++kt) {
        const int cur = kt & 1;
        const unsigned short* As = &Sh[cur][0];
        const unsigned short* Bs = &Sh[cur][4096];
        __syncthreads();
        if (kt + 1 < NSTEP) {
            const int k1 = (kt + 1) * 32;
            load_lds16(Ag + k1, &Sh[cur ^ 1][aOff]);
            load_lds16(Ag + k1 + (size_t)16 * K, &Sh[cur ^ 1][aOff + 512]);
            load_lds16(Bg + k1, &Sh[cur ^ 1][4096 + bOff]);
        }
        short8 af[4], bf[2];
#pragma unroll
        for (int i = 0; i < 4; ++i)
            af[i] = *(const short8*)&As[(wm + i * 16 + l15) * 32 + quad * 8];
#pragma unroll
        for (int i = 0; i < 2; ++i)
            bf[i] = *(const short8*)&Bs[(wn + i * 16 + l15) * 32 + quad * 8];
        __builtin_amdgcn_s_setprio(1);
#pragma unroll
        for (int mt = 0; mt < 4; ++mt)
#pragma unroll
            for (int nt = 0; nt < 2; ++nt)
                acc[mt][nt] = __builtin_amdgcn_mfma_f32_16x16x32_bf16(af[mt], bf[nt], acc[mt][nt], 0, 0, 0);
        __builtin_amdgcn_s_setprio(0);
    }
#pragma unroll
    for (int mt = 0; mt < 4; ++mt) {
        int mrow = m0 + wm + mt * 16 + quad * 4;
#pragma unroll
        for (int nt = 0; nt < 2; ++nt) {
            int col = n0 + wn + nt * 16 + l15;
            float bv = bias[col];
#pragma unroll
            for (int r = 0; r < 4; ++r)
                C[(size_t)(mrow + r) * N + col] = acc[mt][nt][r] + bv;
        }
    }
}

// ---------------------------------------------------------------- flash attention r14 (32x32 core)
// Swapped QK^T with 32x32x16: s[nt] = mfma(K_tile_nt, Q) -> lane (l31, half)
// reg r holds P[k = 32*nt + (r&3)+8*(r>>2)+4*half][q = l31].  Lane-local
// row-sum (q = l31).  PV A-frag for k-window km (16 wide): frag dwords
// [u0,u1,v0,v1] where (u,v) = permlane32_swap(lowgrp_dw, highgrp_dw) — the
// swap's two results are exactly what half=0 / half=1 lanes need (verified
// case-by-case against the m74/m101 C/D layout). No cndmask, no ds_swizzle.
// K/V LDS: stride 64 shorts (128B), 16B-chunk XOR swizzle  c ^= row&7  on
// both write and read sides -> even bank distribution for b128 ops.
__global__ __launch_bounds__(256) void attn4(
    const unsigned short* __restrict__ qk,   // [B*S][2048], head h: [h*128+q | +64 k]
    const unsigned short* __restrict__ Vt,   // [B*H][64][2048]
    unsigned short* __restrict__ out) {      // [B*S][1024]
    const int S = 2048;
    __shared__ unsigned short Ks[2][4096];       // [buf][64 rows x 64 cols], swizzled
    __shared__ unsigned short Vts[2][4096];
    const int t = threadIdx.x, wave = t >> 6, lane = t & 63;
    const int l31 = lane & 31, half = lane >> 5;
    const int bid = blockIdx.x;
    const int qt = (bid < 256) ? (15 - (bid >> 5)) : ((bid - 256) >> 5);
    const int bh = bid & 31;
    const int b = bh >> 4, h = bh & 15;
    const unsigned short* qkb = qk + (size_t)b * S * 2048 + h * 128;
    const unsigned short* vtb = Vt + (size_t)bh * 64 * 2048;

    const int q0 = qt * 128 + wave * 32;         // wave's 32 q-rows
    short8 qf[4];                                // Q[q=l31][d = km*16 + half*8 + j]
#pragma unroll
    for (int km = 0; km < 4; ++km)
        qf[km] = *(const short8*)(qkb + (size_t)(q0 + l31) * 2048 + km * 16 + half * 8);

    f32x16 o[2] = {};
    float lrun = 0.f;

    // staging: 256 threads x 2 x 16B per tensor; rows 0..63, chunk pairs
    const int srow = t >> 2;
    const int c16a = (t & 3) * 2, c16b = c16a + 1;
    const int swzA = srow * 64 + ((c16a ^ (srow & 7)) * 8);
    const int swzB = srow * 64 + ((c16b ^ (srow & 7)) * 8);
    const int KT = qt * 2 + 2;

    uint4 kr0 = *(const uint4*)(qkb + (size_t)srow * 2048 + 64 + c16a * 8);
    uint4 kr1 = *(const uint4*)(qkb + (size_t)srow * 2048 + 64 + c16b * 8);
    uint4 vr0 = *(const uint4*)(vtb + (size_t)srow * 2048 + c16a * 8);
    uint4 vr1 = *(const uint4*)(vtb + (size_t)srow * 2048 + c16b * 8);

    const int qmax = q0 + 31;
    const int ksw = l31 & 7;
    int chs[4];                                  // per-km swizzled chunk byte offsets (shorts)
#pragma unroll
    for (int km = 0; km < 4; ++km)
        chs[km] = ((km * 2 + half) ^ ksw) * 8;
    const int krow = l31 * 64;

    for (int kt = 0; kt < KT; ++kt) {
        const int cur = kt & 1;
        *(uint4*)&Ks[cur][swzA] = kr0;
        *(uint4*)&Ks[cur][swzB] = kr1;
        *(uint4*)&Vts[cur][swzA] = vr0;
        *(uint4*)&Vts[cur][swzB] = vr1;
        __syncthreads();
        if (kt + 1 < KT) {
            const int kn = (kt + 1) * 64;
            kr0 = *(const uint4*)(qkb + (size_t)(kn + srow) * 2048 + 64 + c16a * 8);
            kr1 = *(const uint4*)(qkb + (size_t)(kn + srow) * 2048 + 64 + c16b * 8);
            vr0 = *(const uint4*)(vtb + (size_t)srow * 2048 + kn + c16a * 8);
            vr1 = *(const uint4*)(vtb + (size_t)srow * 2048 + kn + c16b * 8);
        }
        const int kb = kt * 64;
        if (kb > qmax) continue;   // fully masked for this wave; barrier already done

        // ---- QK^T (swapped, 32x32x16): 2 k-tiles x 4 d-windows
        f32x16 s[2] = {};
        __builtin_amdgcn_s_setprio(1);
#pragma unroll
        for (int nt = 0; nt < 2; ++nt)
#pragma unroll
            for (int km = 0; km < 4; ++km) {
                short8 kf = *(const short8*)&Ks[cur][nt * 2048 + krow + chs[km]];
                s[nt] = __builtin_amdgcn_mfma_f32_32x32x16_bf16(kf, qf[km], s[nt], 0, 0, 0);
            }
        __builtin_amdgcn_s_setprio(0);

        // ---- causal mask (diag region only); Q pre-scaled so s is final logit
        if (kb + 63 > q0) {
#pragma unroll
            for (int nt = 0; nt < 2; ++nt)
#pragma unroll
                for (int r = 0; r < 16; ++r) {
                    int kg = kb + nt * 32 + (r & 3) + 8 * (r >> 2) + 4 * half;
                    if (kg > q0 + l31) s[nt][r] = -1e30f;
                }
        }

        // ---- softmax (no-max) + pack, fully in registers
        int gd[2][4][2];                         // [nt][group=reg/4][dword]
        float a0 = 0.f;
#pragma unroll
        for (int nt = 0; nt < 2; ++nt)
#pragma unroll
            for (int g = 0; g < 4; ++g) {
                float e0 = __expf(s[nt][4 * g + 0]);
                float e1 = __expf(s[nt][4 * g + 1]);
                float e2 = __expf(s[nt][4 * g + 2]);
                float e3 = __expf(s[nt][4 * g + 3]);
                a0 += (e0 + e1) + (e2 + e3);
                gd[nt][g][0] = cvt_pk_bf16(e0, e1);
                gd[nt][g][1] = cvt_pk_bf16(e2, e3);
            }
        lrun += a0;

        // ---- PV A-frags: 2 permlane32_swap per k-window, no selects
        short8 paf[4];
#pragma unroll
        for (int km = 0; km < 4; ++km) {
            const int nt = km >> 1, m = km & 1;
            uint2v w0 = __builtin_amdgcn_permlane32_swap(
                (unsigned)gd[nt][2 * m][0], (unsigned)gd[nt][2 * m + 1][0], false, false);
            uint2v w1 = __builtin_amdgcn_permlane32_swap(
                (unsigned)gd[nt][2 * m][1], (unsigned)gd[nt][2 * m + 1][1], false, false);
            int4 v = {(int)w0[0], (int)w1[0], (int)w0[1], (int)w1[1]};
            paf[km] = __builtin_bit_cast(short8, v);
        }

        // ---- PV (32x32x16): 2 d-tiles x 4 k-windows
        __builtin_amdgcn_s_setprio(1);
#pragma unroll
        for (int nt2 = 0; nt2 < 2; ++nt2)
#pragma unroll
            for (int km = 0; km < 4; ++km) {
                short8 vf = *(const short8*)&Vts[cur][nt2 * 2048 + krow + chs[km]];
                o[nt2] = __builtin_amdgcn_mfma_f32_32x32x16_bf16(paf[km], vf, o[nt2], 0, 0, 0);
            }
        __builtin_amdgcn_s_setprio(0);
    }

    // ---- epilogue: halves hold complementary k-subsets for q=l31
    float tot = lrun + __shfl_xor(lrun, 32);
    unsigned short* ob = out + (size_t)b * S * 1024 + h * 64;
#pragma unroll
    for (int r = 0; r < 16; ++r) {
        int ql = (r & 3) + 8 * (r >> 2) + 4 * half;     // output q-row of reg r
        float inv = 1.0f / __shfl(tot, ql);             // sum for q=ql lives at lane l31==ql
        size_t row = (size_t)(q0 + ql) * 1024;
        ob[row + l31] = f2bf(o[0][r] * inv);
        ob[row + 32 + l31] = f2bf(o[1][r] * inv);
    }
}

// ----------------------------------------------------------------
extern "C" void kernel_launch(void* const* d_in, const int* in_sizes, int n_in,
                              void* d_out, int out_size, void* d_ws, size_t ws_size,
                              hipStream_t stream) {
    const float* hs     = (const float*)d_in[0];
    const float* W_attn = (const float*)d_in[1];
    const float* b_attn = (const float*)d_in[2];
    const float* W_proj = (const float*)d_in[3];
    const float* b_proj = (const float*)d_in[4];
    float* out = (float*)d_out;

    const int B = 2, S = 2048, E = 1024;
    const int M = B * S;        // 4096
    const int N3 = 3 * E;       // 3072

    unsigned short* Xb  = (unsigned short*)d_ws;          // M*E
    unsigned short* WaT = Xb + (size_t)M * E;             // N3*E
    unsigned short* WpT = WaT + (size_t)N3 * E;           // E*E
    unsigned short* qkb = WpT + (size_t)E * E;            // M*2048
    unsigned short* Vt  = qkb + (size_t)M * 2048;         // M*E
    unsigned short* ao  = Vt + (size_t)M * E;             // M*E

    prep<<<dim3(8192), 256, 0, stream>>>(hs, Xb, W_attn, WaT, W_proj, WpT);

    gemm_qkv<<<dim3(N3 / 128, M / 128), 256, 0, stream>>>(Xb, WaT, b_attn, qkb, Vt, M, N3, E);

    attn4<<<dim3(512), 256, 0, stream>>>(qkb, Vt, ao);

    gemm_proj<<<dim3(E / 64, M / 128), 256, 0, stream>>>(ao, WpT, b_proj, out, M, E, E);
}

// Round 5
// 168.078 us; speedup vs baseline: 1.1653x; 1.0420x over previous
//
#include <hip/hip_runtime.h>
#include <hip/hip_bf16.h>

// GPT2 attention, B=2 S=2048 E=1024 H=16 hd=64.
// prep (cast X + transpose both weights); MFMA GEMM qkv r13 (128x128, dbuf
// global_load_lds, 1 barrier/k-step, Q pre-scaled by 0.125*log2e, LDS-
// transposed Vt); flash attention r15: 32x32x16 core, 8 waves = 2 k-parity
// groups x 4 q-strips (split-k inside block: group g computes tiles kt%2==g),
// swapped QK^T -> P k-major in regs, exp2 softmax, 2-permlane frag build,
// XOR-swizzled K/V LDS, pair staging + reg prefetch, additive partial
// combine in epilogue; proj GEMM r13 (dbuf). 4 launches.

typedef __attribute__((ext_vector_type(4))) float f32x4;
typedef __attribute__((ext_vector_type(16))) float f32x16;
typedef __attribute__((ext_vector_type(8))) short short8;
typedef __attribute__((ext_vector_type(2))) unsigned int uint2v;

#define AS1 __attribute__((address_space(1)))
#define AS3 __attribute__((address_space(3)))

__device__ __forceinline__ void load_lds16(const void* g, void* l) {
    __builtin_amdgcn_global_load_lds((const AS1 void*)g, (AS3 void*)l, 16, 0, 0);
}

__device__ __forceinline__ unsigned short f2bf(float f) {       // RNE
    union { float f; unsigned int u; } v; v.f = f;
    unsigned int r = v.u + 0x7FFFu + ((v.u >> 16) & 1u);
    return (unsigned short)(r >> 16);
}

__device__ __forceinline__ int cvt_pk_bf16(float lo, float hi) {  // [bf16(lo) | bf16(hi)<<16]
    int r;
    asm("v_cvt_pk_bf16_f32 %0, %1, %2" : "=v"(r) : "v"(lo), "v"(hi));
    return r;
}

__device__ __forceinline__ float fexp2(float x) {               // 2^x
    float r;
    asm("v_exp_f32 %0, %1" : "=v"(r) : "v"(x));
    return r;
}

// ---------------------------------------------------------------- prep: cast + weight transposes
__device__ __forceinline__ void transpose_tile(
    const float* __restrict__ W, unsigned short* __restrict__ Wt,
    int K, int N, int bx, int by, int t) {
    __shared__ float tile[32][33];
    int k0 = by * 32, n0 = bx * 32;
    int r = t >> 3, c = (t & 7) * 4;
    float4 v = *(const float4*)&W[(size_t)(k0 + r) * N + n0 + c];
    tile[r][c] = v.x; tile[r][c + 1] = v.y; tile[r][c + 2] = v.z; tile[r][c + 3] = v.w;
    __syncthreads();
    int n = t >> 3; int kk = (t & 7) * 4;
    ushort4 o;
    o.x = f2bf(tile[kk + 0][n]);
    o.y = f2bf(tile[kk + 1][n]);
    o.z = f2bf(tile[kk + 2][n]);
    o.w = f2bf(tile[kk + 3][n]);
    *(ushort4*)&Wt[(size_t)(n0 + n) * K + k0 + kk] = o;
}

// grid 8192: [0,4096) cast X; [4096,7168) transpose W_attn; [7168,8192) transpose W_proj
__global__ __launch_bounds__(256) void prep(
    const float* __restrict__ hs, unsigned short* __restrict__ Xb,
    const float* __restrict__ W_attn, unsigned short* __restrict__ WaT,
    const float* __restrict__ W_proj, unsigned short* __restrict__ WpT) {
    int bid = blockIdx.x, t = threadIdx.x;
    if (bid < 4096) {
        int i = (bid * 256 + t) * 4;
        float4 v = *(const float4*)(hs + i);
        ushort4 o;
        o.x = f2bf(v.x); o.y = f2bf(v.y); o.z = f2bf(v.z); o.w = f2bf(v.w);
        *(ushort4*)(Xb + i) = o;
    } else if (bid < 7168) {
        int r = bid - 4096;                       // dims (96, 32)
        transpose_tile(W_attn, WaT, 1024, 3072, r % 96, r / 96, t);
    } else {
        int r = bid - 7168;                       // dims (32, 32)
        transpose_tile(W_proj, WpT, 1024, 1024, r % 32, r / 32, t);
    }
}

// ---------------------------------------------------------------- qkv GEMM r13 (128x128, dbuf)
__global__ __launch_bounds__(256) void gemm_qkv(
    const unsigned short* __restrict__ A,
    const unsigned short* __restrict__ Bt,
    const float* __restrict__ bias,
    unsigned short* __restrict__ qk, unsigned short* __restrict__ Vt,
    int M, int N, int K) {
    __shared__ unsigned short Sh[2][8192];       // [buf][As 4096 | Bs 4096]; Tb[64][136] overlays
    unsigned short* Tb = &Sh[0][0];
    const int t = threadIdx.x, wave = t >> 6, lane = t & 63;
    const int l15 = lane & 15, quad = lane >> 4;
    const int m0 = blockIdx.y * 128, n0 = blockIdx.x * 128;
    const int srow = wave * 32 + (lane >> 2);
    const int sch = (lane & 3) * 8;
    const unsigned short* Ag = A + (size_t)(m0 + srow) * K + sch;
    const unsigned short* Bg = Bt + (size_t)(n0 + srow) * K + sch;
    const int wOff = wave * 1024;                // per-wave 32x32 stage region
    const int wm = (wave >> 1) * 64, wn = (wave & 1) * 64;
    f32x4 acc[4][4] = {};
    const int NSTEP = K / 32;                    // 32
    load_lds16(Ag, &Sh[0][wOff]);
    load_lds16(Ag + (size_t)16 * K, &Sh[0][wOff + 512]);
    load_lds16(Bg, &Sh[0][4096 + wOff]);
    load_lds16(Bg + (size_t)16 * K, &Sh[0][4096 + wOff + 512]);
    for (int kt = 0; kt < NSTEP; ++kt) {
        const int cur = kt & 1;
        const unsigned short* As = &Sh[cur][0];
        const unsigned short* Bs = &Sh[cur][4096];
        __syncthreads();                         // buf[cur] ready; buf[cur^1] reads done
        if (kt + 1 < NSTEP) {
            const int k1 = (kt + 1) * 32;
            unsigned short* An = &Sh[cur ^ 1][0];
            unsigned short* Bn = &Sh[cur ^ 1][4096];
            load_lds16(Ag + k1, An + wOff);
            load_lds16(Ag + k1 + (size_t)16 * K, An + wOff + 512);
            load_lds16(Bg + k1, Bn + wOff);
            load_lds16(Bg + k1 + (size_t)16 * K, Bn + wOff + 512);
        }
        short8 af[4], bf[4];
#pragma unroll
        for (int i = 0; i < 4; ++i) {
            af[i] = *(const short8*)&As[(wm + i * 16 + l15) * 32 + quad * 8];
            bf[i] = *(const short8*)&Bs[(wn + i * 16 + l15) * 32 + quad * 8];
        }
        __builtin_amdgcn_s_setprio(1);
#pragma unroll
        for (int mt = 0; mt < 4; ++mt)
#pragma unroll
            for (int nt = 0; nt < 4; ++nt)
                acc[mt][nt] = __builtin_amdgcn_mfma_f32_16x16x32_bf16(af[mt], bf[nt], acc[mt][nt], 0, 0, 0);
        __builtin_amdgcn_s_setprio(0);
    }
    __syncthreads();                             // all k-loop LDS reads done before Tb overlay
    const int rem = n0 % 192;                    // 0: no V; 128: half 0 is V; 64: half 1 is V
#pragma unroll
    for (int mt = 0; mt < 4; ++mt) {
        int mrow = m0 + wm + mt * 16 + quad * 4;
#pragma unroll
        for (int nt = 0; nt < 4; ++nt) {
            int col = n0 + wn + nt * 16 + l15;
            float bv = bias[col];
            int h = col / 192;
            int j = col - h * 192;
            if (j < 128) {       // Q or K -> qk buffer (both land at h*128 + j)
                // fold 1/sqrt(hd) AND log2(e) into Q so attn softmax is raw exp2
                float sc = (j < 64) ? 0.18033688011f : 1.0f;
#pragma unroll
                for (int r = 0; r < 4; ++r)
                    qk[(size_t)(mrow + r) * 2048 + h * 128 + j] = f2bf((acc[mt][nt][r] + bv) * sc);
            } else {             // V -> LDS transpose buffer Tb[d][s_local]
                int d = j - 128;
                int s_local = wm + mt * 16 + quad * 4;
                ushort4 pk;
                pk.x = f2bf(acc[mt][nt][0] + bv);
                pk.y = f2bf(acc[mt][nt][1] + bv);
                pk.z = f2bf(acc[mt][nt][2] + bv);
                pk.w = f2bf(acc[mt][nt][3] + bv);
                *(ushort4*)&Tb[d * 136 + s_local] = pk;
            }
        }
    }
    if (rem != 0) {              // block-uniform: barrier legal
        __syncthreads();
        int vhalf = (rem == 64) ? 1 : 0;
        int h = (n0 + vhalf * 64) / 192;
        int b = m0 >> 11;
        unsigned short* vbase = Vt + ((size_t)(b * 16 + h) * 64) * 2048 + (m0 & 2047);
        int drow = t >> 4, ch = (t & 15) * 8;    // 16 rows/pass x 16 chunks of 16B
#pragma unroll
        for (int rr = 0; rr < 4; ++rr) {
            int d = rr * 16 + drow;
            *(uint4*)(vbase + (size_t)d * 2048 + ch) = *(const uint4*)&Tb[d * 136 + ch];
        }
    }
}

// ---------------------------------------------------------------- proj GEMM r13, 128x64 tile, dbuf
__global__ __launch_bounds__(256) void gemm_proj(
    const unsigned short* __restrict__ A,
    const unsigned short* __restrict__ Bt,
    const float* __restrict__ bias,
    float* __restrict__ C, int M, int N, int K) {
    __shared__ unsigned short Sh[2][6144];       // [buf][As 4096 | Bs 2048]
    const int t = threadIdx.x, wave = t >> 6, lane = t & 63;
    const int l15 = lane & 15, quad = lane >> 4;
    const int m0 = blockIdx.y * 128, n0 = blockIdx.x * 64;
    const int srowA = wave * 32 + (lane >> 2);
    const int sch = (lane & 3) * 8;
    const unsigned short* Ag = A + (size_t)(m0 + srowA) * K + sch;
    const unsigned short* Bg = Bt + (size_t)(n0 + wave * 16 + (lane >> 2)) * K + sch;
    const int aOff = wave * 1024, bOff = wave * 512;
    const int wm = (wave >> 1) * 64, wn = (wave & 1) * 32;
    f32x4 acc[4][2] = {};
    const int NSTEP = K / 32;
    load_lds16(Ag, &Sh[0][aOff]);
    load_lds16(Ag + (size_t)16 * K, &Sh[0][aOff + 512]);
    load_lds16(Bg, &Sh[0][4096 + bOff]);
    for (int kt = 0; kt < NSTEP; ++kt) {
        const int cur = kt & 1;
        const unsigned short* As = &Sh[cur][0];
        const unsigned short* Bs = &Sh[cur][4096];
        __syncthreads();
        if (kt + 1 < NSTEP) {
            const int k1 = (kt + 1) * 32;
            load_lds16(Ag + k1, &Sh[cur ^ 1][aOff]);
            load_lds16(Ag + k1 + (size_t)16 * K, &Sh[cur ^ 1][aOff + 512]);
            load_lds16(Bg + k1, &Sh[cur ^ 1][4096 + bOff]);
        }
        short8 af[4], bf[2];
#pragma unroll
        for (int i = 0; i < 4; ++i)
            af[i] = *(const short8*)&As[(wm + i * 16 + l15) * 32 + quad * 8];
#pragma unroll
        for (int i = 0; i < 2; ++i)
            bf[i] = *(const short8*)&Bs[(wn + i * 16 + l15) * 32 + quad * 8];
        __builtin_amdgcn_s_setprio(1);
#pragma unroll
        for (int mt = 0; mt < 4; ++mt)
#pragma unroll
            for (int nt = 0; nt < 2; ++nt)
                acc[mt][nt] = __builtin_amdgcn_mfma_f32_16x16x32_bf16(af[mt], bf[nt], acc[mt][nt], 0, 0, 0);
        __builtin_amdgcn_s_setprio(0);
    }
#pragma unroll
    for (int mt = 0; mt < 4; ++mt) {
        int mrow = m0 + wm + mt * 16 + quad * 4;
#pragma unroll
        for (int nt = 0; nt < 2; ++nt) {
            int col = n0 + wn + nt * 16 + l15;
            float bv = bias[col];
#pragma unroll
            for (int r = 0; r < 4; ++r)
                C[(size_t)(mrow + r) * N + col] = acc[mt][nt][r] + bv;
        }
    }
}

// ---------------------------------------------------------------- flash attention r15
// 32x32x16 swapped core (layout as r14, harness-verified).  8 waves = 2
// k-parity groups x 4 q-strips of 32 rows.  Per pair of k-tiles: stage all 4
// sub-tiles (K/V x even/odd) -> barrier -> group g computes tile 2p+g ->
// barrier.  Serial k-chain per wave is halved and waves/CU doubled vs r14.
// No-max softmax => partials combine additively across groups (LDS, 2 phases).
__global__ __launch_bounds__(512, 4) void attn5(
    const unsigned short* __restrict__ qk,   // [B*S][2048], head h: [h*128+q | +64 k]
    const unsigned short* __restrict__ Vt,   // [B*H][64][2048]
    unsigned short* __restrict__ out) {      // [B*S][1024]
    const int S = 2048;
    __shared__ unsigned short Sh[16384];         // KE|KO|VE|VO, each 64x64 swizzled (32KB)
    const int t = threadIdx.x, wave = t >> 6, lane = t & 63;
    const int l31 = lane & 31, half = lane >> 5;
    const int g = wave >> 2, gw = wave & 3;      // k-parity group, wave-in-group
    const int bid = blockIdx.x;
    const int qt = (bid < 256) ? (15 - (bid >> 5)) : ((bid - 256) >> 5);
    const int bh = bid & 31;
    const int b = bh >> 4, h = bh & 15;
    const unsigned short* qkb = qk + (size_t)b * S * 2048 + h * 128;
    const unsigned short* vtb = Vt + (size_t)bh * 64 * 2048;

    const int q0 = qt * 128 + gw * 32;           // this wave's 32 q-rows
    short8 qf[4];                                // Q[q=l31][d = km*16 + half*8 + j]
#pragma unroll
    for (int km = 0; km < 4; ++km)
        qf[km] = *(const short8*)(qkb + (size_t)(q0 + l31) * 2048 + km * 16 + half * 8);

    f32x16 o[2] = {};
    float lrun = 0.f;

    // staging: 512 threads x 1 chunk (16B) per sub-tile; rows 0..63, 8 chunks/row
    const int srow = t >> 3, ch16 = t & 7;
    const int swz = srow * 64 + ((ch16 ^ (srow & 7)) * 8);
    const int KTP = qt + 1;                      // pairs of k-tiles

    uint4 kE = *(const uint4*)(qkb + (size_t)srow * 2048 + 64 + ch16 * 8);
    uint4 kO = *(const uint4*)(qkb + (size_t)(64 + srow) * 2048 + 64 + ch16 * 8);
    uint4 vE = *(const uint4*)(vtb + (size_t)srow * 2048 + ch16 * 8);
    uint4 vO = *(const uint4*)(vtb + (size_t)srow * 2048 + 64 + ch16 * 8);

    const int qmax = q0 + 31;
    const int ksw = l31 & 7;
    int chs[4];                                  // per-km swizzled chunk offsets (shorts)
#pragma unroll
    for (int km = 0; km < 4; ++km)
        chs[km] = ((km * 2 + half) ^ ksw) * 8;
    const int krow = l31 * 64;
    const unsigned short* Ksg = Sh + (g ? 4096 : 0);
    const unsigned short* Vsg = Sh + 8192 + (g ? 4096 : 0);

    for (int p = 0; p < KTP; ++p) {
        *(uint4*)&Sh[swz] = kE;
        *(uint4*)&Sh[4096 + swz] = kO;
        *(uint4*)&Sh[8192 + swz] = vE;
        *(uint4*)&Sh[12288 + swz] = vO;
        __syncthreads();
        if (p + 1 < KTP) {
            const int k2 = (2 * p + 2) * 64, k3 = k2 + 64;
            kE = *(const uint4*)(qkb + (size_t)(k2 + srow) * 2048 + 64 + ch16 * 8);
            kO = *(const uint4*)(qkb + (size_t)(k3 + srow) * 2048 + 64 + ch16 * 8);
            vE = *(const uint4*)(vtb + (size_t)srow * 2048 + k2 + ch16 * 8);
            vO = *(const uint4*)(vtb + (size_t)srow * 2048 + k3 + ch16 * 8);
        }
        const int kb = (2 * p + g) * 64;
        if (kb <= qmax) {
            // ---- QK^T (swapped, 32x32x16): 2 k-subtiles x 4 d-windows
            f32x16 s[2] = {};
            __builtin_amdgcn_s_setprio(1);
#pragma unroll
            for (int nt = 0; nt < 2; ++nt)
#pragma unroll
                for (int km = 0; km < 4; ++km) {
                    short8 kf = *(const short8*)&Ksg[nt * 2048 + krow + chs[km]];
                    s[nt] = __builtin_amdgcn_mfma_f32_32x32x16_bf16(kf, qf[km], s[nt], 0, 0, 0);
                }
            __builtin_amdgcn_s_setprio(0);

            // ---- causal mask (diag region only); Q pre-scaled so s is log2-logit
            if (kb + 63 > q0) {
#pragma unroll
                for (int nt = 0; nt < 2; ++nt)
#pragma unroll
                    for (int r = 0; r < 16; ++r) {
                        int kg = kb + nt * 32 + (r & 3) + 8 * (r >> 2) + 4 * half;
                        if (kg > q0 + l31) s[nt][r] = -1e30f;
                    }
            }

            // ---- softmax (no-max, exp2) + pack, fully in registers
            int gd[2][4][2];                     // [nt][reg-group][dword]
            float a0 = 0.f;
#pragma unroll
            for (int nt = 0; nt < 2; ++nt)
#pragma unroll
                for (int gg = 0; gg < 4; ++gg) {
                    float e0 = fexp2(s[nt][4 * gg + 0]);
                    float e1 = fexp2(s[nt][4 * gg + 1]);
                    float e2 = fexp2(s[nt][4 * gg + 2]);
                    float e3 = fexp2(s[nt][4 * gg + 3]);
                    a0 += (e0 + e1) + (e2 + e3);
                    gd[nt][gg][0] = cvt_pk_bf16(e0, e1);
                    gd[nt][gg][1] = cvt_pk_bf16(e2, e3);
                }
            lrun += a0;

            // ---- PV A-frags: 2 permlane32_swap per k-window
            short8 paf[4];
#pragma unroll
            for (int km = 0; km < 4; ++km) {
                const int nt = km >> 1, m = km & 1;
                uint2v w0 = __builtin_amdgcn_permlane32_swap(
                    (unsigned)gd[nt][2 * m][0], (unsigned)gd[nt][2 * m + 1][0], false, false);
                uint2v w1 = __builtin_amdgcn_permlane32_swap(
                    (unsigned)gd[nt][2 * m][1], (unsigned)gd[nt][2 * m + 1][1], false, false);
                int4 v = {(int)w0[0], (int)w1[0], (int)w0[1], (int)w1[1]};
                paf[km] = __builtin_bit_cast(short8, v);
            }

            // ---- PV (32x32x16): 2 d-subtiles x 4 k-windows
            __builtin_amdgcn_s_setprio(1);
#pragma unroll
            for (int nt2 = 0; nt2 < 2; ++nt2)
#pragma unroll
                for (int km = 0; km < 4; ++km) {
                    short8 vf = *(const short8*)&Vsg[nt2 * 2048 + krow + chs[km]];
                    o[nt2] = __builtin_amdgcn_mfma_f32_32x32x16_bf16(paf[km], vf, o[nt2], 0, 0, 0);
                }
            __builtin_amdgcn_s_setprio(0);
        }
        __syncthreads();                         // LDS reads done before next pair's writes
    }

    // ---- epilogue: combine group partials additively (no-max softmax), then store
    float* Lf = (float*)Sh;
    const int cidx = gw * 64 + lane;
    if (g == 1) {
        float* dst = Lf + cidx * 17;
#pragma unroll
        for (int r = 0; r < 16; ++r) dst[r] = o[0][r];
        dst[16] = lrun;
    }
    __syncthreads();
    float lsum = lrun;
    if (g == 0) {
        const float* src = Lf + cidx * 17;
#pragma unroll
        for (int r = 0; r < 16; ++r) o[0][r] += src[r];
        lsum += src[16];
    }
    __syncthreads();
    if (g == 1) {
        float* dst = Lf + cidx * 16;
#pragma unroll
        for (int r = 0; r < 16; ++r) dst[r] = o[1][r];
    }
    __syncthreads();
    if (g == 0) {
        const float* src = Lf + cidx * 16;
#pragma unroll
        for (int r = 0; r < 16; ++r) o[1][r] += src[r];
        float tot = lsum + __shfl_xor(lsum, 32);
        unsigned short* ob = out + (size_t)b * S * 1024 + h * 64;
#pragma unroll
        for (int r = 0; r < 16; ++r) {
            int ql = (r & 3) + 8 * (r >> 2) + 4 * half;   // output q-row of reg r
            float inv = 1.0f / __shfl(tot, ql);           // sum for q=ql at lane l31==ql
            size_t row = (size_t)(q0 + ql) * 1024;
            ob[row + l31] = f2bf(o[0][r] * inv);
            ob[row + 32 + l31] = f2bf(o[1][r] * inv);
        }
    }
}

// ----------------------------------------------------------------
extern "C" void kernel_launch(void* const* d_in, const int* in_sizes, int n_in,
                              void* d_out, int out_size, void* d_ws, size_t ws_size,
                              hipStream_t stream) {
    const float* hs     = (const float*)d_in[0];
    const float* W_attn = (const float*)d_in[1];
    const float* b_attn = (const float*)d_in[2];
    const float* W_proj = (const float*)d_in[3];
    const float* b_proj = (const float*)d_in[4];
    float* out = (float*)d_out;

    const int B = 2, S = 2048, E = 1024;
    const int M = B * S;        // 4096
    const int N3 = 3 * E;       // 3072

    unsigned short* Xb  = (unsigned short*)d_ws;          // M*E
    unsigned short* WaT = Xb + (size_t)M * E;             // N3*E
    unsigned short* WpT = WaT + (size_t)N3 * E;           // E*E
    unsigned short* qkb = WpT + (size_t)E * E;            // M*2048
    unsigned short* Vt  = qkb + (size_t)M * 2048;         // M*E
    unsigned short* ao  = Vt + (size_t)M * E;             // M*E

    prep<<<dim3(8192), 256, 0, stream>>>(hs, Xb, W_attn, WaT, W_proj, WpT);

    gemm_qkv<<<dim3(N3 / 128, M / 128), 256, 0, stream>>>(Xb, WaT, b_attn, qkb, Vt, M, N3, E);

    attn5<<<dim3(512), 512, 0, stream>>>(qkb, Vt, ao);

    gemm_proj<<<dim3(E / 64, M / 128), 256, 0, stream>>>(ao, WpT, b_proj, out, M, E, E);
}

// Round 6
// 167.217 us; speedup vs baseline: 1.1713x; 1.0051x over previous
//
#include <hip/hip_runtime.h>
#include <hip/hip_bf16.h>

// GPT2 attention, B=2 S=2048 E=1024 H=16 hd=64.
// prep (cast X + transpose both weights); MFMA GEMM qkv r16: 128x128 tile,
// 512 threads = 8 waves x (32x64), dbuf global_load_lds, 1 barrier/k-step,
// Q pre-scaled by 0.125*log2e, LDS-transposed Vt.  flash attention r15
// (unchanged): 32x32x16 core, 2 k-parity groups x 4 q-strips, swapped QK^T,
// exp2 softmax, 2-permlane frag build, XOR-swizzled LDS.  proj GEMM r16:
// 128x64, 512 threads = 8 waves x (32x32), dbuf. 4 launches.

typedef __attribute__((ext_vector_type(4))) float f32x4;
typedef __attribute__((ext_vector_type(16))) float f32x16;
typedef __attribute__((ext_vector_type(8))) short short8;
typedef __attribute__((ext_vector_type(2))) unsigned int uint2v;

#define AS1 __attribute__((address_space(1)))
#define AS3 __attribute__((address_space(3)))

__device__ __forceinline__ void load_lds16(const void* g, void* l) {
    __builtin_amdgcn_global_load_lds((const AS1 void*)g, (AS3 void*)l, 16, 0, 0);
}

__device__ __forceinline__ unsigned short f2bf(float f) {       // RNE
    union { float f; unsigned int u; } v; v.f = f;
    unsigned int r = v.u + 0x7FFFu + ((v.u >> 16) & 1u);
    return (unsigned short)(r >> 16);
}

__device__ __forceinline__ int cvt_pk_bf16(float lo, float hi) {  // [bf16(lo) | bf16(hi)<<16]
    int r;
    asm("v_cvt_pk_bf16_f32 %0, %1, %2" : "=v"(r) : "v"(lo), "v"(hi));
    return r;
}

__device__ __forceinline__ float fexp2(float x) {               // 2^x
    float r;
    asm("v_exp_f32 %0, %1" : "=v"(r) : "v"(x));
    return r;
}

// ---------------------------------------------------------------- prep: cast + weight transposes
__device__ __forceinline__ void transpose_tile(
    const float* __restrict__ W, unsigned short* __restrict__ Wt,
    int K, int N, int bx, int by, int t) {
    __shared__ float tile[32][33];
    int k0 = by * 32, n0 = bx * 32;
    int r = t >> 3, c = (t & 7) * 4;
    float4 v = *(const float4*)&W[(size_t)(k0 + r) * N + n0 + c];
    tile[r][c] = v.x; tile[r][c + 1] = v.y; tile[r][c + 2] = v.z; tile[r][c + 3] = v.w;
    __syncthreads();
    int n = t >> 3; int kk = (t & 7) * 4;
    ushort4 o;
    o.x = f2bf(tile[kk + 0][n]);
    o.y = f2bf(tile[kk + 1][n]);
    o.z = f2bf(tile[kk + 2][n]);
    o.w = f2bf(tile[kk + 3][n]);
    *(ushort4*)&Wt[(size_t)(n0 + n) * K + k0 + kk] = o;
}

// grid 8192: [0,4096) cast X; [4096,7168) transpose W_attn; [7168,8192) transpose W_proj
__global__ __launch_bounds__(256) void prep(
    const float* __restrict__ hs, unsigned short* __restrict__ Xb,
    const float* __restrict__ W_attn, unsigned short* __restrict__ WaT,
    const float* __restrict__ W_proj, unsigned short* __restrict__ WpT) {
    int bid = blockIdx.x, t = threadIdx.x;
    if (bid < 4096) {
        int i = (bid * 256 + t) * 4;
        float4 v = *(const float4*)(hs + i);
        ushort4 o;
        o.x = f2bf(v.x); o.y = f2bf(v.y); o.z = f2bf(v.z); o.w = f2bf(v.w);
        *(ushort4*)(Xb + i) = o;
    } else if (bid < 7168) {
        int r = bid - 4096;                       // dims (96, 32)
        transpose_tile(W_attn, WaT, 1024, 3072, r % 96, r / 96, t);
    } else {
        int r = bid - 7168;                       // dims (32, 32)
        transpose_tile(W_proj, WpT, 1024, 1024, r % 32, r / 32, t);
    }
}

// ---------------------------------------------------------------- qkv GEMM r16 (128x128, 8 waves, dbuf)
// C = Xb @ WaT^T + bias; qkv split -> qk[s][h*128+(q|k)] bf16 (Q cols scaled
// by 0.125*log2e); V -> Vt[b][h][d][s] via LDS transpose.  8 waves: wave w
// computes rows [(w>>1)*32, +32) x cols [(w&1)*64, +64); waves 0-3 stage A,
// 4-7 stage B.  Dbuf, one barrier per k-step.
__global__ __launch_bounds__(512, 6) void gemm_qkv(
    const unsigned short* __restrict__ A,
    const unsigned short* __restrict__ Bt,
    const float* __restrict__ bias,
    unsigned short* __restrict__ qk, unsigned short* __restrict__ Vt,
    int M, int N, int K) {
    __shared__ unsigned short Sh[2][8192];       // [buf][As 4096 | Bs 4096]; Tb[64][136] overlays
    unsigned short* Tb = &Sh[0][0];
    const int t = threadIdx.x, wave = t >> 6, lane = t & 63;
    const int l15 = lane & 15, quad = lane >> 4;
    const int m0 = blockIdx.y * 128, n0 = blockIdx.x * 128;
    // staging: waves 0-3 -> A rows [sw*32,+32); waves 4-7 -> B rows [sw*32,+32)
    const int sw = wave & 3;
    const bool isB = wave >= 4;
    const int srow = sw * 32 + (lane >> 2);
    const int sch = (lane & 3) * 8;
    const unsigned short* G0 = isB ? (Bt + (size_t)(n0 + srow) * K + sch)
                                   : (A + (size_t)(m0 + srow) * K + sch);
    const int stOff = (isB ? 4096 : 0) + sw * 1024;
    const int wr = wave >> 1, wc = wave & 1;     // 4x2 wave grid, 32x64 each
    f32x4 acc[2][4] = {};
    const int NSTEP = K / 32;                    // 32
    load_lds16(G0, &Sh[0][stOff]);
    load_lds16(G0 + (size_t)16 * K, &Sh[0][stOff + 512]);
    for (int kt = 0; kt < NSTEP; ++kt) {
        const int cur = kt & 1;
        const unsigned short* As = &Sh[cur][0];
        const unsigned short* Bs = &Sh[cur][4096];
        __syncthreads();                         // buf[cur] ready; buf[cur^1] reads done
        if (kt + 1 < NSTEP) {
            const int k1 = (kt + 1) * 32;
            load_lds16(G0 + k1, &Sh[cur ^ 1][stOff]);
            load_lds16(G0 + k1 + (size_t)16 * K, &Sh[cur ^ 1][stOff + 512]);
        }
        short8 af[2], bf[4];
#pragma unroll
        for (int i = 0; i < 2; ++i)
            af[i] = *(const short8*)&As[(wr * 32 + i * 16 + l15) * 32 + quad * 8];
#pragma unroll
        for (int i = 0; i < 4; ++i)
            bf[i] = *(const short8*)&Bs[(wc * 64 + i * 16 + l15) * 32 + quad * 8];
        __builtin_amdgcn_s_setprio(1);
#pragma unroll
        for (int mt = 0; mt < 2; ++mt)
#pragma unroll
            for (int nt = 0; nt < 4; ++nt)
                acc[mt][nt] = __builtin_amdgcn_mfma_f32_16x16x32_bf16(af[mt], bf[nt], acc[mt][nt], 0, 0, 0);
        __builtin_amdgcn_s_setprio(0);
    }
    __syncthreads();                             // all k-loop LDS reads done before Tb overlay
    const int rem = n0 % 192;                    // 0: no V; 128: half 0 is V; 64: half 1 is V
#pragma unroll
    for (int mt = 0; mt < 2; ++mt) {
        int mrow = m0 + wr * 32 + mt * 16 + quad * 4;
#pragma unroll
        for (int nt = 0; nt < 4; ++nt) {
            int col = n0 + wc * 64 + nt * 16 + l15;
            float bv = bias[col];
            int h = col / 192;
            int j = col - h * 192;
            if (j < 128) {       // Q or K -> qk buffer (both land at h*128 + j)
                // fold 1/sqrt(hd) AND log2(e) into Q so attn softmax is raw exp2
                float sc = (j < 64) ? 0.18033688011f : 1.0f;
#pragma unroll
                for (int r = 0; r < 4; ++r)
                    qk[(size_t)(mrow + r) * 2048 + h * 128 + j] = f2bf((acc[mt][nt][r] + bv) * sc);
            } else {             // V -> LDS transpose buffer Tb[d][s_local]
                int d = j - 128;
                int s_local = wr * 32 + mt * 16 + quad * 4;
                ushort4 pk;
                pk.x = f2bf(acc[mt][nt][0] + bv);
                pk.y = f2bf(acc[mt][nt][1] + bv);
                pk.z = f2bf(acc[mt][nt][2] + bv);
                pk.w = f2bf(acc[mt][nt][3] + bv);
                *(ushort4*)&Tb[d * 136 + s_local] = pk;
            }
        }
    }
    if (rem != 0) {              // block-uniform: barrier legal
        __syncthreads();
        int vhalf = (rem == 64) ? 1 : 0;
        int h = (n0 + vhalf * 64) / 192;
        int b = m0 >> 11;
        unsigned short* vbase = Vt + ((size_t)(b * 16 + h) * 64) * 2048 + (m0 & 2047);
        int drow = t >> 4, ch = (t & 15) * 8;    // 32 rows/pass x 16 chunks of 16B
#pragma unroll
        for (int rr = 0; rr < 2; ++rr) {
            int d = rr * 32 + drow;
            *(uint4*)(vbase + (size_t)d * 2048 + ch) = *(const uint4*)&Tb[d * 136 + ch];
        }
    }
}

// ---------------------------------------------------------------- proj GEMM r16, 128x64, 8 waves, dbuf
__global__ __launch_bounds__(512, 4) void gemm_proj(
    const unsigned short* __restrict__ A,
    const unsigned short* __restrict__ Bt,
    const float* __restrict__ bias,
    float* __restrict__ C, int M, int N, int K) {
    __shared__ unsigned short Sh[2][6144];       // [buf][As 4096 | Bs 2048]
    const int t = threadIdx.x, wave = t >> 6, lane = t & 63;
    const int l15 = lane & 15, quad = lane >> 4;
    const int m0 = blockIdx.y * 128, n0 = blockIdx.x * 64;
    const int sw = wave & 3;
    const bool isB = wave >= 4;
    const int srow = isB ? (sw * 16 + (lane >> 2)) : (sw * 32 + (lane >> 2));
    const int sch = (lane & 3) * 8;
    const unsigned short* G0 = isB ? (Bt + (size_t)(n0 + srow) * K + sch)
                                   : (A + (size_t)(m0 + srow) * K + sch);
    const int stOff = isB ? (4096 + sw * 512) : (sw * 1024);
    const int wr = wave >> 1, wc = wave & 1;     // 4x2 wave grid, 32x32 each
    f32x4 acc[2][2] = {};
    const int NSTEP = K / 32;
    load_lds16(G0, &Sh[0][stOff]);
    if (!isB) load_lds16(G0 + (size_t)16 * K, &Sh[0][stOff + 512]);
    for (int kt = 0; kt < NSTEP; ++kt) {
        const int cur = kt & 1;
        const unsigned short* As = &Sh[cur][0];
        const unsigned short* Bs = &Sh[cur][4096];
        __syncthreads();
        if (kt + 1 < NSTEP) {
            const int k1 = (kt + 1) * 32;
            load_lds16(G0 + k1, &Sh[cur ^ 1][stOff]);
            if (!isB) load_lds16(G0 + k1 + (size_t)16 * K, &Sh[cur ^ 1][stOff + 512]);
        }
        short8 af[2], bf[2];
#pragma unroll
        for (int i = 0; i < 2; ++i)
            af[i] = *(const short8*)&As[(wr * 32 + i * 16 + l15) * 32 + quad * 8];
#pragma unroll
        for (int i = 0; i < 2; ++i)
            bf[i] = *(const short8*)&Bs[(wc * 32 + i * 16 + l15) * 32 + quad * 8];
        __builtin_amdgcn_s_setprio(1);
#pragma unroll
        for (int mt = 0; mt < 2; ++mt)
#pragma unroll
            for (int nt = 0; nt < 2; ++nt)
                acc[mt][nt] = __builtin_amdgcn_mfma_f32_16x16x32_bf16(af[mt], bf[nt], acc[mt][nt], 0, 0, 0);
        __builtin_amdgcn_s_setprio(0);
    }
#pragma unroll
    for (int mt = 0; mt < 2; ++mt) {
        int mrow = m0 + wr * 32 + mt * 16 + quad * 4;
#pragma unroll
        for (int nt = 0; nt < 2; ++nt) {
            int col = n0 + wc * 32 + nt * 16 + l15;
            float bv = bias[col];
#pragma unroll
            for (int r = 0; r < 4; ++r)
                C[(size_t)(mrow + r) * N + col] = acc[mt][nt][r] + bv;
        }
    }
}

// ---------------------------------------------------------------- flash attention r15 (unchanged)
// 32x32x16 swapped core.  8 waves = 2 k-parity groups x 4 q-strips of 32 rows.
// Per pair of k-tiles: stage all 4 sub-tiles -> barrier -> group g computes
// tile 2p+g -> barrier.  No-max softmax => additive partial combine.
__global__ __launch_bounds__(512, 4) void attn5(
    const unsigned short* __restrict__ qk,   // [B*S][2048], head h: [h*128+q | +64 k]
    const unsigned short* __restrict__ Vt,   // [B*H][64][2048]
    unsigned short* __restrict__ out) {      // [B*S][1024]
    const int S = 2048;
    __shared__ unsigned short Sh[16384];         // KE|KO|VE|VO, each 64x64 swizzled (32KB)
    const int t = threadIdx.x, wave = t >> 6, lane = t & 63;
    const int l31 = lane & 31, half = lane >> 5;
    const int g = wave >> 2, gw = wave & 3;      // k-parity group, wave-in-group
    const int bid = blockIdx.x;
    const int qt = (bid < 256) ? (15 - (bid >> 5)) : ((bid - 256) >> 5);
    const int bh = bid & 31;
    const int b = bh >> 4, h = bh & 15;
    const unsigned short* qkb = qk + (size_t)b * S * 2048 + h * 128;
    const unsigned short* vtb = Vt + (size_t)bh * 64 * 2048;

    const int q0 = qt * 128 + gw * 32;           // this wave's 32 q-rows
    short8 qf[4];                                // Q[q=l31][d = km*16 + half*8 + j]
#pragma unroll
    for (int km = 0; km < 4; ++km)
        qf[km] = *(const short8*)(qkb + (size_t)(q0 + l31) * 2048 + km * 16 + half * 8);

    f32x16 o[2] = {};
    float lrun = 0.f;

    // staging: 512 threads x 1 chunk (16B) per sub-tile; rows 0..63, 8 chunks/row
    const int srow = t >> 3, ch16 = t & 7;
    const int swz = srow * 64 + ((ch16 ^ (srow & 7)) * 8);
    const int KTP = qt + 1;                      // pairs of k-tiles

    uint4 kE = *(const uint4*)(qkb + (size_t)srow * 2048 + 64 + ch16 * 8);
    uint4 kO = *(const uint4*)(qkb + (size_t)(64 + srow) * 2048 + 64 + ch16 * 8);
    uint4 vE = *(const uint4*)(vtb + (size_t)srow * 2048 + ch16 * 8);
    uint4 vO = *(const uint4*)(vtb + (size_t)srow * 2048 + 64 + ch16 * 8);

    const int qmax = q0 + 31;
    const int ksw = l31 & 7;
    int chs[4];                                  // per-km swizzled chunk offsets (shorts)
#pragma unroll
    for (int km = 0; km < 4; ++km)
        chs[km] = ((km * 2 + half) ^ ksw) * 8;
    const int krow = l31 * 64;
    const unsigned short* Ksg = Sh + (g ? 4096 : 0);
    const unsigned short* Vsg = Sh + 8192 + (g ? 4096 : 0);

    for (int p = 0; p < KTP; ++p) {
        *(uint4*)&Sh[swz] = kE;
        *(uint4*)&Sh[4096 + swz] = kO;
        *(uint4*)&Sh[8192 + swz] = vE;
        *(uint4*)&Sh[12288 + swz] = vO;
        __syncthreads();
        if (p + 1 < KTP) {
            const int k2 = (2 * p + 2) * 64, k3 = k2 + 64;
            kE = *(const uint4*)(qkb + (size_t)(k2 + srow) * 2048 + 64 + ch16 * 8);
            kO = *(const uint4*)(qkb + (size_t)(k3 + srow) * 2048 + 64 + ch16 * 8);
            vE = *(const uint4*)(vtb + (size_t)srow * 2048 + k2 + ch16 * 8);
            vO = *(const uint4*)(vtb + (size_t)srow * 2048 + k3 + ch16 * 8);
        }
        const int kb = (2 * p + g) * 64;
        if (kb <= qmax) {
            // ---- QK^T (swapped, 32x32x16): 2 k-subtiles x 4 d-windows
            f32x16 s[2] = {};
            __builtin_amdgcn_s_setprio(1);
#pragma unroll
            for (int nt = 0; nt < 2; ++nt)
#pragma unroll
                for (int km = 0; km < 4; ++km) {
                    short8 kf = *(const short8*)&Ksg[nt * 2048 + krow + chs[km]];
                    s[nt] = __builtin_amdgcn_mfma_f32_32x32x16_bf16(kf, qf[km], s[nt], 0, 0, 0);
                }
            __builtin_amdgcn_s_setprio(0);

            // ---- causal mask (diag region only); Q pre-scaled so s is log2-logit
            if (kb + 63 > q0) {
#pragma unroll
                for (int nt = 0; nt < 2; ++nt)
#pragma unroll
                    for (int r = 0; r < 16; ++r) {
                        int kg = kb + nt * 32 + (r & 3) + 8 * (r >> 2) + 4 * half;
                        if (kg > q0 + l31) s[nt][r] = -1e30f;
                    }
            }

            // ---- softmax (no-max, exp2) + pack, fully in registers
            int gd[2][4][2];                     // [nt][reg-group][dword]
            float a0 = 0.f;
#pragma unroll
            for (int nt = 0; nt < 2; ++nt)
#pragma unroll
                for (int gg = 0; gg < 4; ++gg) {
                    float e0 = fexp2(s[nt][4 * gg + 0]);
                    float e1 = fexp2(s[nt][4 * gg + 1]);
                    float e2 = fexp2(s[nt][4 * gg + 2]);
                    float e3 = fexp2(s[nt][4 * gg + 3]);
                    a0 += (e0 + e1) + (e2 + e3);
                    gd[nt][gg][0] = cvt_pk_bf16(e0, e1);
                    gd[nt][gg][1] = cvt_pk_bf16(e2, e3);
                }
            lrun += a0;

            // ---- PV A-frags: 2 permlane32_swap per k-window
            short8 paf[4];
#pragma unroll
            for (int km = 0; km < 4; ++km) {
                const int nt = km >> 1, m = km & 1;
                uint2v w0 = __builtin_amdgcn_permlane32_swap(
                    (unsigned)gd[nt][2 * m][0], (unsigned)gd[nt][2 * m + 1][0], false, false);
                uint2v w1 = __builtin_amdgcn_permlane32_swap(
                    (unsigned)gd[nt][2 * m][1], (unsigned)gd[nt][2 * m + 1][1], false, false);
                int4 v = {(int)w0[0], (int)w1[0], (int)w0[1], (int)w1[1]};
                paf[km] = __builtin_bit_cast(short8, v);
            }

            // ---- PV (32x32x16): 2 d-subtiles x 4 k-windows
            __builtin_amdgcn_s_setprio(1);
#pragma unroll
            for (int nt2 = 0; nt2 < 2; ++nt2)
#pragma unroll
                for (int km = 0; km < 4; ++km) {
                    short8 vf = *(const short8*)&Vsg[nt2 * 2048 + krow + chs[km]];
                    o[nt2] = __builtin_amdgcn_mfma_f32_32x32x16_bf16(paf[km], vf, o[nt2], 0, 0, 0);
                }
            __builtin_amdgcn_s_setprio(0);
        }
        __syncthreads();                         // LDS reads done before next pair's writes
    }

    // ---- epilogue: combine group partials additively (no-max softmax), then store
    float* Lf = (float*)Sh;
    const int cidx = gw * 64 + lane;
    if (g == 1) {
        float* dst = Lf + cidx * 17;
#pragma unroll
        for (int r = 0; r < 16; ++r) dst[r] = o[0][r];
        dst[16] = lrun;
    }
    __syncthreads();
    float lsum = lrun;
    if (g == 0) {
        const float* src = Lf + cidx * 17;
#pragma unroll
        for (int r = 0; r < 16; ++r) o[0][r] += src[r];
        lsum += src[16];
    }
    __syncthreads();
    if (g == 1) {
        float* dst = Lf + cidx * 16;
#pragma unroll
        for (int r = 0; r < 16; ++r) dst[r] = o[1][r];
    }
    __syncthreads();
    if (g == 0) {
        const float* src = Lf + cidx * 16;
#pragma unroll
        for (int r = 0; r < 16; ++r) o[1][r] += src[r];
        float tot = lsum + __shfl_xor(lsum, 32);
        unsigned short* ob = out + (size_t)b * S * 1024 + h * 64;
#pragma unroll
        for (int r = 0; r < 16; ++r) {
            int ql = (r & 3) + 8 * (r >> 2) + 4 * half;   // output q-row of reg r
            float inv = 1.0f / __shfl(tot, ql);           // sum for q=ql at lane l31==ql
            size_t row = (size_t)(q0 + ql) * 1024;
            ob[row + l31] = f2bf(o[0][r] * inv);
            ob[row + 32 + l31] = f2bf(o[1][r] * inv);
        }
    }
}

// ----------------------------------------------------------------
extern "C" void kernel_launch(void* const* d_in, const int* in_sizes, int n_in,
                              void* d_out, int out_size, void* d_ws, size_t ws_size,
                              hipStream_t stream) {
    const float* hs     = (const float*)d_in[0];
    const float* W_attn = (const float*)d_in[1];
    const float* b_attn = (const float*)d_in[2];
    const float* W_proj = (const float*)d_in[3];
    const float* b_proj = (const float*)d_in[4];
    float* out = (float*)d_out;

    const int B = 2, S = 2048, E = 1024;
    const int M = B * S;        // 4096
    const int N3 = 3 * E;       // 3072

    unsigned short* Xb  = (unsigned short*)d_ws;          // M*E
    unsigned short* WaT = Xb + (size_t)M * E;             // N3*E
    unsigned short* WpT = WaT + (size_t)N3 * E;           // E*E
    unsigned short* qkb = WpT + (size_t)E * E;            // M*2048
    unsigned short* Vt  = qkb + (size_t)M * 2048;         // M*E
    unsigned short* ao  = Vt + (size_t)M * E;             // M*E

    prep<<<dim3(8192), 256, 0, stream>>>(hs, Xb, W_attn, WaT, W_proj, WpT);

    gemm_qkv<<<dim3(N3 / 128, M / 128), 512, 0, stream>>>(Xb, WaT, b_attn, qkb, Vt, M, N3, E);

    attn5<<<dim3(512), 512, 0, stream>>>(qkb, Vt, ao);

    gemm_proj<<<dim3(E / 64, M / 128), 512, 0, stream>>>(ao, WpT, b_proj, out, M, E, E);
}

// Round 7
// 164.593 us; speedup vs baseline: 1.1899x; 1.0159x over previous
//
#include <hip/hip_runtime.h>
#include <hip/hip_bf16.h>

// GPT2 attention, B=2 S=2048 E=1024 H=16 hd=64.
// prep (cast X + transpose both weights); MFMA GEMM qkv r16 (128x128, 8 waves,
// dbuf global_load_lds, 1 barrier/k-step, Q pre-scaled 0.125*log2e, LDS-
// transposed Vt); flash attention r17: 32x32x16 core, 2 k-parity groups x 4
// q-strips, swapped QK^T, exp2 softmax, 2-permlane frag build; staging now
// global_load_lds into 64KB double buffer (linear LDS dest + inverse-swizzled
// per-lane global source), ONE barrier per pair-step; proj GEMM r16. 4 launches.

typedef __attribute__((ext_vector_type(4))) float f32x4;
typedef __attribute__((ext_vector_type(16))) float f32x16;
typedef __attribute__((ext_vector_type(8))) short short8;
typedef __attribute__((ext_vector_type(2))) unsigned int uint2v;

#define AS1 __attribute__((address_space(1)))
#define AS3 __attribute__((address_space(3)))

__device__ __forceinline__ void load_lds16(const void* g, void* l) {
    __builtin_amdgcn_global_load_lds((const AS1 void*)g, (AS3 void*)l, 16, 0, 0);
}

__device__ __forceinline__ unsigned short f2bf(float f) {       // RNE
    union { float f; unsigned int u; } v; v.f = f;
    unsigned int r = v.u + 0x7FFFu + ((v.u >> 16) & 1u);
    return (unsigned short)(r >> 16);
}

__device__ __forceinline__ int cvt_pk_bf16(float lo, float hi) {  // [bf16(lo) | bf16(hi)<<16]
    int r;
    asm("v_cvt_pk_bf16_f32 %0, %1, %2" : "=v"(r) : "v"(lo), "v"(hi));
    return r;
}

__device__ __forceinline__ float fexp2(float x) {               // 2^x
    float r;
    asm("v_exp_f32 %0, %1" : "=v"(r) : "v"(x));
    return r;
}

// ---------------------------------------------------------------- prep: cast + weight transposes
__device__ __forceinline__ void transpose_tile(
    const float* __restrict__ W, unsigned short* __restrict__ Wt,
    int K, int N, int bx, int by, int t) {
    __shared__ float tile[32][33];
    int k0 = by * 32, n0 = bx * 32;
    int r = t >> 3, c = (t & 7) * 4;
    float4 v = *(const float4*)&W[(size_t)(k0 + r) * N + n0 + c];
    tile[r][c] = v.x; tile[r][c + 1] = v.y; tile[r][c + 2] = v.z; tile[r][c + 3] = v.w;
    __syncthreads();
    int n = t >> 3; int kk = (t & 7) * 4;
    ushort4 o;
    o.x = f2bf(tile[kk + 0][n]);
    o.y = f2bf(tile[kk + 1][n]);
    o.z = f2bf(tile[kk + 2][n]);
    o.w = f2bf(tile[kk + 3][n]);
    *(ushort4*)&Wt[(size_t)(n0 + n) * K + k0 + kk] = o;
}

// grid 8192: [0,4096) cast X; [4096,7168) transpose W_attn; [7168,8192) transpose W_proj
__global__ __launch_bounds__(256) void prep(
    const float* __restrict__ hs, unsigned short* __restrict__ Xb,
    const float* __restrict__ W_attn, unsigned short* __restrict__ WaT,
    const float* __restrict__ W_proj, unsigned short* __restrict__ WpT) {
    int bid = blockIdx.x, t = threadIdx.x;
    if (bid < 4096) {
        int i = (bid * 256 + t) * 4;
        float4 v = *(const float4*)(hs + i);
        ushort4 o;
        o.x = f2bf(v.x); o.y = f2bf(v.y); o.z = f2bf(v.z); o.w = f2bf(v.w);
        *(ushort4*)(Xb + i) = o;
    } else if (bid < 7168) {
        int r = bid - 4096;                       // dims (96, 32)
        transpose_tile(W_attn, WaT, 1024, 3072, r % 96, r / 96, t);
    } else {
        int r = bid - 7168;                       // dims (32, 32)
        transpose_tile(W_proj, WpT, 1024, 1024, r % 32, r / 32, t);
    }
}

// ---------------------------------------------------------------- qkv GEMM r16 (128x128, 8 waves, dbuf)
__global__ __launch_bounds__(512, 6) void gemm_qkv(
    const unsigned short* __restrict__ A,
    const unsigned short* __restrict__ Bt,
    const float* __restrict__ bias,
    unsigned short* __restrict__ qk, unsigned short* __restrict__ Vt,
    int M, int N, int K) {
    __shared__ unsigned short Sh[2][8192];       // [buf][As 4096 | Bs 4096]; Tb[64][136] overlays
    unsigned short* Tb = &Sh[0][0];
    const int t = threadIdx.x, wave = t >> 6, lane = t & 63;
    const int l15 = lane & 15, quad = lane >> 4;
    const int m0 = blockIdx.y * 128, n0 = blockIdx.x * 128;
    const int sw = wave & 3;
    const bool isB = wave >= 4;
    const int srow = sw * 32 + (lane >> 2);
    const int sch = (lane & 3) * 8;
    const unsigned short* G0 = isB ? (Bt + (size_t)(n0 + srow) * K + sch)
                                   : (A + (size_t)(m0 + srow) * K + sch);
    const int stOff = (isB ? 4096 : 0) + sw * 1024;
    const int wr = wave >> 1, wc = wave & 1;     // 4x2 wave grid, 32x64 each
    f32x4 acc[2][4] = {};
    const int NSTEP = K / 32;                    // 32
    load_lds16(G0, &Sh[0][stOff]);
    load_lds16(G0 + (size_t)16 * K, &Sh[0][stOff + 512]);
    for (int kt = 0; kt < NSTEP; ++kt) {
        const int cur = kt & 1;
        const unsigned short* As = &Sh[cur][0];
        const unsigned short* Bs = &Sh[cur][4096];
        __syncthreads();                         // buf[cur] ready; buf[cur^1] reads done
        if (kt + 1 < NSTEP) {
            const int k1 = (kt + 1) * 32;
            load_lds16(G0 + k1, &Sh[cur ^ 1][stOff]);
            load_lds16(G0 + k1 + (size_t)16 * K, &Sh[cur ^ 1][stOff + 512]);
        }
        short8 af[2], bf[4];
#pragma unroll
        for (int i = 0; i < 2; ++i)
            af[i] = *(const short8*)&As[(wr * 32 + i * 16 + l15) * 32 + quad * 8];
#pragma unroll
        for (int i = 0; i < 4; ++i)
            bf[i] = *(const short8*)&Bs[(wc * 64 + i * 16 + l15) * 32 + quad * 8];
        __builtin_amdgcn_s_setprio(1);
#pragma unroll
        for (int mt = 0; mt < 2; ++mt)
#pragma unroll
            for (int nt = 0; nt < 4; ++nt)
                acc[mt][nt] = __builtin_amdgcn_mfma_f32_16x16x32_bf16(af[mt], bf[nt], acc[mt][nt], 0, 0, 0);
        __builtin_amdgcn_s_setprio(0);
    }
    __syncthreads();                             // all k-loop LDS reads done before Tb overlay
    const int rem = n0 % 192;                    // 0: no V; 128: half 0 is V; 64: half 1 is V
#pragma unroll
    for (int mt = 0; mt < 2; ++mt) {
        int mrow = m0 + wr * 32 + mt * 16 + quad * 4;
#pragma unroll
        for (int nt = 0; nt < 4; ++nt) {
            int col = n0 + wc * 64 + nt * 16 + l15;
            float bv = bias[col];
            int h = col / 192;
            int j = col - h * 192;
            if (j < 128) {       // Q or K -> qk buffer (both land at h*128 + j)
                // fold 1/sqrt(hd) AND log2(e) into Q so attn softmax is raw exp2
                float sc = (j < 64) ? 0.18033688011f : 1.0f;
#pragma unroll
                for (int r = 0; r < 4; ++r)
                    qk[(size_t)(mrow + r) * 2048 + h * 128 + j] = f2bf((acc[mt][nt][r] + bv) * sc);
            } else {             // V -> LDS transpose buffer Tb[d][s_local]
                int d = j - 128;
                int s_local = wr * 32 + mt * 16 + quad * 4;
                ushort4 pk;
                pk.x = f2bf(acc[mt][nt][0] + bv);
                pk.y = f2bf(acc[mt][nt][1] + bv);
                pk.z = f2bf(acc[mt][nt][2] + bv);
                pk.w = f2bf(acc[mt][nt][3] + bv);
                *(ushort4*)&Tb[d * 136 + s_local] = pk;
            }
        }
    }
    if (rem != 0) {              // block-uniform: barrier legal
        __syncthreads();
        int vhalf = (rem == 64) ? 1 : 0;
        int h = (n0 + vhalf * 64) / 192;
        int b = m0 >> 11;
        unsigned short* vbase = Vt + ((size_t)(b * 16 + h) * 64) * 2048 + (m0 & 2047);
        int drow = t >> 4, ch = (t & 15) * 8;    // 32 rows/pass x 16 chunks of 16B
#pragma unroll
        for (int rr = 0; rr < 2; ++rr) {
            int d = rr * 32 + drow;
            *(uint4*)(vbase + (size_t)d * 2048 + ch) = *(const uint4*)&Tb[d * 136 + ch];
        }
    }
}

// ---------------------------------------------------------------- proj GEMM r16, 128x64, 8 waves, dbuf
__global__ __launch_bounds__(512, 4) void gemm_proj(
    const unsigned short* __restrict__ A,
    const unsigned short* __restrict__ Bt,
    const float* __restrict__ bias,
    float* __restrict__ C, int M, int N, int K) {
    __shared__ unsigned short Sh[2][6144];       // [buf][As 4096 | Bs 2048]
    const int t = threadIdx.x, wave = t >> 6, lane = t & 63;
    const int l15 = lane & 15, quad = lane >> 4;
    const int m0 = blockIdx.y * 128, n0 = blockIdx.x * 64;
    const int sw = wave & 3;
    const bool isB = wave >= 4;
    const int srow = isB ? (sw * 16 + (lane >> 2)) : (sw * 32 + (lane >> 2));
    const int sch = (lane & 3) * 8;
    const unsigned short* G0 = isB ? (Bt + (size_t)(n0 + srow) * K + sch)
                                   : (A + (size_t)(m0 + srow) * K + sch);
    const int stOff = isB ? (4096 + sw * 512) : (sw * 1024);
    const int wr = wave >> 1, wc = wave & 1;     // 4x2 wave grid, 32x32 each
    f32x4 acc[2][2] = {};
    const int NSTEP = K / 32;
    load_lds16(G0, &Sh[0][stOff]);
    if (!isB) load_lds16(G0 + (size_t)16 * K, &Sh[0][stOff + 512]);
    for (int kt = 0; kt < NSTEP; ++kt) {
        const int cur = kt & 1;
        const unsigned short* As = &Sh[cur][0];
        const unsigned short* Bs = &Sh[cur][4096];
        __syncthreads();
        if (kt + 1 < NSTEP) {
            const int k1 = (kt + 1) * 32;
            load_lds16(G0 + k1, &Sh[cur ^ 1][stOff]);
            if (!isB) load_lds16(G0 + k1 + (size_t)16 * K, &Sh[cur ^ 1][stOff + 512]);
        }
        short8 af[2], bf[2];
#pragma unroll
        for (int i = 0; i < 2; ++i)
            af[i] = *(const short8*)&As[(wr * 32 + i * 16 + l15) * 32 + quad * 8];
#pragma unroll
        for (int i = 0; i < 2; ++i)
            bf[i] = *(const short8*)&Bs[(wc * 32 + i * 16 + l15) * 32 + quad * 8];
        __builtin_amdgcn_s_setprio(1);
#pragma unroll
        for (int mt = 0; mt < 2; ++mt)
#pragma unroll
            for (int nt = 0; nt < 2; ++nt)
                acc[mt][nt] = __builtin_amdgcn_mfma_f32_16x16x32_bf16(af[mt], bf[nt], acc[mt][nt], 0, 0, 0);
        __builtin_amdgcn_s_setprio(0);
    }
#pragma unroll
    for (int mt = 0; mt < 2; ++mt) {
        int mrow = m0 + wr * 32 + mt * 16 + quad * 4;
#pragma unroll
        for (int nt = 0; nt < 2; ++nt) {
            int col = n0 + wc * 32 + nt * 16 + l15;
            float bv = bias[col];
#pragma unroll
            for (int r = 0; r < 4; ++r)
                C[(size_t)(mrow + r) * N + col] = acc[mt][nt][r] + bv;
        }
    }
}

// ---------------------------------------------------------------- flash attention r17
// 32x32x16 swapped core.  8 waves = 2 k-parity groups x 4 q-strips of 32 rows.
// Staging via global_load_lds into 64KB double buffer: LDS dest is LINEAR
// (wave-uniform base + lane*16B); the XOR bank swizzle is applied by
// inverse-swizzling the per-lane GLOBAL source chunk (m173 pattern), so the
// read-side XOR (chs[]) sees the same layout as before.  One barrier per
// pair-step: barrier (drains pair p loads) -> issue p+1 loads -> compute p.
__global__ __launch_bounds__(512, 4) void attn6(
    const unsigned short* __restrict__ qk,   // [B*S][2048], head h: [h*128+q | +64 k]
    const unsigned short* __restrict__ Vt,   // [B*H][64][2048]
    unsigned short* __restrict__ out) {      // [B*S][1024]
    const int S = 2048;
    __shared__ unsigned short Sh[2][16384];      // [buf][KE|KO|VE|VO], each 64x64 swizzled
    const int t = threadIdx.x, wave = t >> 6, lane = t & 63;
    const int l31 = lane & 31, half = lane >> 5;
    const int g = wave >> 2, gw = wave & 3;      // k-parity group, wave-in-group
    const int bid = blockIdx.x;
    const int qt = (bid < 256) ? (15 - (bid >> 5)) : ((bid - 256) >> 5);
    const int bh = bid & 31;
    const int b = bh >> 4, h = bh & 15;
    const unsigned short* qkb = qk + (size_t)b * S * 2048 + h * 128;
    const unsigned short* vtb = Vt + (size_t)bh * 64 * 2048;

    const int q0 = qt * 128 + gw * 32;           // this wave's 32 q-rows
    short8 qf[4];                                // Q[q=l31][d = km*16 + half*8 + j]
#pragma unroll
    for (int km = 0; km < 4; ++km)
        qf[km] = *(const short8*)(qkb + (size_t)(q0 + l31) * 2048 + km * 16 + half * 8);

    f32x16 o[2] = {};
    float lrun = 0.f;

    // staging: thread t covers sub-tile row srow = t>>3, chunk c8 = t&7.
    // global source chunk inverse-swizzled so linear LDS dest ends up swizzled.
    const int srow = t >> 3, c8 = t & 7;
    const int gsw = ((c8 ^ (srow & 7)) * 8);     // shorts offset within 64-col window
    const int ldst = wave * 512;                 // wave-uniform dest (shorts) per sub-tile
    const unsigned short* kSrc = qkb + (size_t)srow * 2048 + 64 + gsw;
    const unsigned short* vSrc = vtb + (size_t)srow * 2048 + gsw;
    const int KTP = qt + 1;                      // pairs of k-tiles

    // prologue: stage pair 0 into buf 0
    load_lds16(kSrc, &Sh[0][ldst]);
    load_lds16(kSrc + (size_t)64 * 2048, &Sh[0][4096 + ldst]);
    load_lds16(vSrc, &Sh[0][8192 + ldst]);
    load_lds16(vSrc + 64, &Sh[0][12288 + ldst]);

    const int qmax = q0 + 31;
    const int ksw = l31 & 7;
    int chs[4];                                  // per-km swizzled chunk offsets (shorts)
#pragma unroll
    for (int km = 0; km < 4; ++km)
        chs[km] = ((km * 2 + half) ^ ksw) * 8;
    const int krow = l31 * 64;
    const int gOff = g ? 4096 : 0;

    for (int p = 0; p < KTP; ++p) {
        const int cur = p & 1;
        __syncthreads();                         // pair p staged; buf[cur^1] reads (p-1) done
        if (p + 1 < KTP) {
            const int k2 = (2 * p + 2) * 64;
            unsigned short* nb = &Sh[cur ^ 1][0];
            load_lds16(kSrc + (size_t)k2 * 2048, nb + ldst);
            load_lds16(kSrc + (size_t)(k2 + 64) * 2048, nb + 4096 + ldst);
            load_lds16(vSrc + k2, nb + 8192 + ldst);
            load_lds16(vSrc + k2 + 64, nb + 12288 + ldst);
        }
        const int kb = (2 * p + g) * 64;
        if (kb > qmax) continue;                 // fully masked for this wave

        const unsigned short* Ksg = &Sh[cur][gOff];
        const unsigned short* Vsg = &Sh[cur][8192 + gOff];

        // ---- QK^T (swapped, 32x32x16): 2 k-subtiles x 4 d-windows
        f32x16 s[2] = {};
        __builtin_amdgcn_s_setprio(1);
#pragma unroll
        for (int nt = 0; nt < 2; ++nt)
#pragma unroll
            for (int km = 0; km < 4; ++km) {
                short8 kf = *(const short8*)&Ksg[nt * 2048 + krow + chs[km]];
                s[nt] = __builtin_amdgcn_mfma_f32_32x32x16_bf16(kf, qf[km], s[nt], 0, 0, 0);
            }
        __builtin_amdgcn_s_setprio(0);

        // ---- causal mask (diag region only); Q pre-scaled so s is log2-logit
        if (kb + 63 > q0) {
#pragma unroll
            for (int nt = 0; nt < 2; ++nt)
#pragma unroll
                for (int r = 0; r < 16; ++r) {
                    int kg = kb + nt * 32 + (r & 3) + 8 * (r >> 2) + 4 * half;
                    if (kg > q0 + l31) s[nt][r] = -1e30f;
                }
        }

        // ---- softmax (no-max, exp2) + pack, fully in registers
        int gd[2][4][2];                         // [nt][reg-group][dword]
        float a0 = 0.f;
#pragma unroll
        for (int nt = 0; nt < 2; ++nt)
#pragma unroll
            for (int gg = 0; gg < 4; ++gg) {
                float e0 = fexp2(s[nt][4 * gg + 0]);
                float e1 = fexp2(s[nt][4 * gg + 1]);
                float e2 = fexp2(s[nt][4 * gg + 2]);
                float e3 = fexp2(s[nt][4 * gg + 3]);
                a0 += (e0 + e1) + (e2 + e3);
                gd[nt][gg][0] = cvt_pk_bf16(e0, e1);
                gd[nt][gg][1] = cvt_pk_bf16(e2, e3);
            }
        lrun += a0;

        // ---- PV A-frags: 2 permlane32_swap per k-window
        short8 paf[4];
#pragma unroll
        for (int km = 0; km < 4; ++km) {
            const int nt = km >> 1, m = km & 1;
            uint2v w0 = __builtin_amdgcn_permlane32_swap(
                (unsigned)gd[nt][2 * m][0], (unsigned)gd[nt][2 * m + 1][0], false, false);
            uint2v w1 = __builtin_amdgcn_permlane32_swap(
                (unsigned)gd[nt][2 * m][1], (unsigned)gd[nt][2 * m + 1][1], false, false);
            int4 v = {(int)w0[0], (int)w1[0], (int)w0[1], (int)w1[1]};
            paf[km] = __builtin_bit_cast(short8, v);
        }

        // ---- PV (32x32x16): 2 d-subtiles x 4 k-windows
        __builtin_amdgcn_s_setprio(1);
#pragma unroll
        for (int nt2 = 0; nt2 < 2; ++nt2)
#pragma unroll
            for (int km = 0; km < 4; ++km) {
                short8 vf = *(const short8*)&Vsg[nt2 * 2048 + krow + chs[km]];
                o[nt2] = __builtin_amdgcn_mfma_f32_32x32x16_bf16(paf[km], vf, o[nt2], 0, 0, 0);
            }
        __builtin_amdgcn_s_setprio(0);
    }
    __syncthreads();                             // all LDS reads done before epilogue overlay

    // ---- epilogue: combine group partials additively (no-max softmax), then store
    float* Lf = (float*)&Sh[0][0];
    const int cidx = gw * 64 + lane;
    if (g == 1) {
        float* dst = Lf + cidx * 17;
#pragma unroll
        for (int r = 0; r < 16; ++r) dst[r] = o[0][r];
        dst[16] = lrun;
    }
    __syncthreads();
    float lsum = lrun;
    if (g == 0) {
        const float* src = Lf + cidx * 17;
#pragma unroll
        for (int r = 0; r < 16; ++r) o[0][r] += src[r];
        lsum += src[16];
    }
    __syncthreads();
    if (g == 1) {
        float* dst = Lf + cidx * 16;
#pragma unroll
        for (int r = 0; r < 16; ++r) dst[r] = o[1][r];
    }
    __syncthreads();
    if (g == 0) {
        const float* src = Lf + cidx * 16;
#pragma unroll
        for (int r = 0; r < 16; ++r) o[1][r] += src[r];
        float tot = lsum + __shfl_xor(lsum, 32);
        unsigned short* ob = out + (size_t)b * S * 1024 + h * 64;
#pragma unroll
        for (int r = 0; r < 16; ++r) {
            int ql = (r & 3) + 8 * (r >> 2) + 4 * half;   // output q-row of reg r
            float inv = 1.0f / __shfl(tot, ql);           // sum for q=ql at lane l31==ql
            size_t row = (size_t)(q0 + ql) * 1024;
            ob[row + l31] = f2bf(o[0][r] * inv);
            ob[row + 32 + l31] = f2bf(o[1][r] * inv);
        }
    }
}

// ----------------------------------------------------------------
extern "C" void kernel_launch(void* const* d_in, const int* in_sizes, int n_in,
                              void* d_out, int out_size, void* d_ws, size_t ws_size,
                              hipStream_t stream) {
    const float* hs     = (const float*)d_in[0];
    const float* W_attn = (const float*)d_in[1];
    const float* b_attn = (const float*)d_in[2];
    const float* W_proj = (const float*)d_in[3];
    const float* b_proj = (const float*)d_in[4];
    float* out = (float*)d_out;

    const int B = 2, S = 2048, E = 1024;
    const int M = B * S;        // 4096
    const int N3 = 3 * E;       // 3072

    unsigned short* Xb  = (unsigned short*)d_ws;          // M*E
    unsigned short* WaT = Xb + (size_t)M * E;             // N3*E
    unsigned short* WpT = WaT + (size_t)N3 * E;           // E*E
    unsigned short* qkb = WpT + (size_t)E * E;            // M*2048
    unsigned short* Vt  = qkb + (size_t)M * 2048;         // M*E
    unsigned short* ao  = Vt + (size_t)M * E;             // M*E

    prep<<<dim3(8192), 256, 0, stream>>>(hs, Xb, W_attn, WaT, W_proj, WpT);

    gemm_qkv<<<dim3(N3 / 128, M / 128), 512, 0, stream>>>(Xb, WaT, b_attn, qkb, Vt, M, N3, E);

    attn6<<<dim3(512), 512, 0, stream>>>(qkb, Vt, ao);

    gemm_proj<<<dim3(E / 64, M / 128), 512, 0, stream>>>(ao, WpT, b_proj, out, M, E, E);
}